// Round 2
// baseline (634.649 us; speedup 1.0000x reference)
//
#include <hip/hip_runtime.h>
#include <hip/hip_bf16.h>

#define BSZ   2
#define SEQL  4096
#define BLR   8192      // BSZ * SEQL rows
#define DM    192
#define NST   16
#define DTR   12
#define XDW   44        // DTR + 2*NST
#define NCH   32        // scan chunks
#define CT    128       // chunk length (NCH*CT == SEQL)

__device__ __forceinline__ float sigf(float x) { return 1.f / (1.f + __expf(-x)); }
__device__ __forceinline__ float siluf(float x) { return x * sigf(x); }
__device__ __forceinline__ float softplusf(float x) { return x > 20.f ? x : log1pf(__expf(x)); }

// ---------------- LayerNorm over channels: NCHW fp32 -> [BL,192] fp32 ----------------
__global__ __launch_bounds__(256) void ln_kernel(const float* __restrict__ x,
                                                 const float* __restrict__ lw,
                                                 const float* __restrict__ lb,
                                                 float* __restrict__ xn) {
    int row  = blockIdx.x * 4 + (threadIdx.x >> 6);   // one wave per row
    int lane = threadIdx.x & 63;
    int b = row >> 12, hw = row & 4095;
    float v[3];
#pragma unroll
    for (int i = 0; i < 3; i++) {
        int c = lane + (i << 6);
        v[i] = x[(((size_t)b * DM + c) << 12) + hw];
    }
    float s = v[0] + v[1] + v[2];
    float q = v[0] * v[0] + v[1] * v[1] + v[2] * v[2];
#pragma unroll
    for (int m = 32; m > 0; m >>= 1) { s += __shfl_xor(s, m); q += __shfl_xor(q, m); }
    float mu  = s * (1.f / DM);
    float var = q * (1.f / DM) - mu * mu;
    float rs  = rsqrtf(var + 1e-5f);
#pragma unroll
    for (int i = 0; i < 3; i++) {
        int c = lane + (i << 6);
        xn[(size_t)row * DM + c] = (v[i] - mu) * rs * lw[c] + lb[c];
    }
}

// ---------------- generic NT GEMM: C[m,n] = sum_k A[m,k] * W[n,k]  ----------------
// A fp32 (lda), W fp32 row-major (ldw). M fixed at 8192 (grid.y=128, 64-row tiles).
// EPI: 0 plain, 1 +bias, 2 softplus(x+bias), 3 *scalar, 4 final residual (writes fp32 NCHW out)
template <int EPI>
__global__ __launch_bounds__(256) void gemm_nt(const float* __restrict__ A, int lda,
                                               const float* __restrict__ W, int ldw,
                                               float* __restrict__ C, int ldc,
                                               int N, int K,
                                               const float* __restrict__ bias,
                                               const float* __restrict__ scal,
                                               const float* __restrict__ aux,
                                               const float* __restrict__ xres,
                                               float* __restrict__ outp) {
    __shared__ float As[16][68];
    __shared__ float Ws[16][68];
    const int tid = threadIdx.x;
    const int tx = tid & 15, ty = tid >> 4;
    const int m0 = blockIdx.y << 6, n0 = blockIdx.x << 6;
    float acc[4][4] = {};
    for (int k0 = 0; k0 < K; k0 += 16) {
#pragma unroll
        for (int i = 0; i < 4; i++) {
            int lin = (i << 8) + tid;
            int r = lin >> 4, kk = lin & 15;
            float av = 0.f;
            if (k0 + kk < K) av = A[(size_t)(m0 + r) * lda + k0 + kk];
            As[kk][r] = av;
            float wv = 0.f;
            if (n0 + r < N && k0 + kk < K) wv = W[(size_t)(n0 + r) * ldw + k0 + kk];
            Ws[kk][r] = wv;
        }
        __syncthreads();
#pragma unroll
        for (int k = 0; k < 16; k++) {
            float a_[4], b_[4];
#pragma unroll
            for (int i = 0; i < 4; i++) a_[i] = As[k][(ty << 2) + i];
#pragma unroll
            for (int j = 0; j < 4; j++) b_[j] = Ws[k][(tx << 2) + j];
#pragma unroll
            for (int i = 0; i < 4; i++)
#pragma unroll
                for (int j = 0; j < 4; j++) acc[i][j] += a_[i] * b_[j];
        }
        __syncthreads();
    }
#pragma unroll
    for (int i = 0; i < 4; i++) {
        int m = m0 + (ty << 2) + i;
#pragma unroll
        for (int j = 0; j < 4; j++) {
            int n = n0 + (tx << 2) + j;
            if (n >= N) continue;
            float v = acc[i][j];
            if (EPI == 1) v += bias[n];
            if (EPI == 2) v = softplusf(v + bias[n]);
            if (EPI == 3) v *= scal[0];
            if (EPI == 4) {
                float sg  = v + bias[n];
                int b = m >> 12, hw = m & 4095;
                float xmv = aux[(size_t)m * DM + n];
                size_t oi = (((size_t)b * DM + n) << 12) + hw;
                outp[oi] = xres[oi] + scal[0] * (xmv + sg);
                continue;
            }
            C[(size_t)m * ldc + n] = v;
        }
    }
}

// ---------------- causal (dir0) / anti-causal (dir1) depthwise conv4 + SiLU ----------------
__global__ __launch_bounds__(256) void conv_silu_kernel(const float* __restrict__ xz,
                                                        const float* __restrict__ cw0, const float* __restrict__ cb0,
                                                        const float* __restrict__ cw1, const float* __restrict__ cb1,
                                                        float* __restrict__ xc) {
    int idx = blockIdx.x * 256 + threadIdx.x;   // BL*384
    int col = idx % 384;
    int row = idx / 384;
    int dir = col >= DM;
    int d = col - dir * DM;
    int b = row >> 12, l = row & 4095;
    const float* cw = dir ? cw1 : cw0;
    float acc = (dir ? cb1 : cb0)[d];
#pragma unroll
    for (int k = 0; k < 4; k++) {
        float w = cw[d * 4 + k];
        int ls = dir ? (l + 3 - k) : (l - 3 + k);
        if (ls >= 0 && ls < SEQL)
            acc += w * xz[((size_t)(b << 12) + ls) * 768 + dir * 384 + d];
    }
    xc[(size_t)row * 384 + col] = siluf(acc);
}

// ---------------- chunked scan, pass A: per-chunk local state + decay ----------------
__global__ __launch_bounds__(256) void scan_partial(const float* __restrict__ dtb,
                                                    const float* __restrict__ xcb,
                                                    const float* __restrict__ xd0,
                                                    const float* __restrict__ xd1,
                                                    const float* __restrict__ Alog0,
                                                    const float* __restrict__ Alog1,
                                                    float* __restrict__ S, float* __restrict__ P) {
    int gid = blockIdx.x * 256 + threadIdx.x;   // 4*NCH*192*16
    int n = gid & 15;
    int t = gid >> 4;
    int d = t % DM;
    int rem = t / DM;
    int chunk = rem & (NCH - 1);
    int dirb = rem >> 5;
    int b = dirb >> 1, dir = dirb & 1;
    const float* xd = dir ? xd1 : xd0;
    float Av = -__expf((dir ? Alog1 : Alog0)[d * NST + n]);
    float h = 0.f, sdt = 0.f;
    int s0 = chunk * CT;
    int col = dir * DM + d;
#pragma unroll 4
    for (int s = 0; s < CT; s++) {
        int l = dir ? (SEQL - 1 - (s0 + s)) : (s0 + s);
        size_t row = (size_t)(b << 12) + l;
        float dtv = dtb[row * 384 + col];
        float xcv = xcb[row * 384 + col];
        float Bv  = xd[row * XDW + DTR + n];
        h = __expf(dtv * Av) * h + dtv * Bv * xcv;
        sdt += dtv;
    }
    S[gid] = h;
    P[gid] = __expf(Av * sdt);
}

// ---------------- pass B: sequential combine over 32 chunks ----------------
__global__ __launch_bounds__(256) void scan_combine(const float* __restrict__ S,
                                                    const float* __restrict__ P,
                                                    float* __restrict__ Hini) {
    int id = blockIdx.x * 256 + threadIdx.x;    // 4*3072
    int dirb = id / 3072;
    int dn = id % 3072;
    float h = 0.f;
    for (int c = 0; c < NCH; c++) {
        size_t idx = (size_t)(dirb * NCH + c) * 3072 + dn;
        Hini[idx] = h;
        h = P[idx] * h + S[idx];
    }
}

// ---------------- pass C: replay with true init, fused y = (h.C + D*x)*silu(z) ----------------
__global__ __launch_bounds__(256) void scan_final(const float* __restrict__ dtb,
                                                  const float* __restrict__ xcb,
                                                  const float* __restrict__ xd0,
                                                  const float* __restrict__ xd1,
                                                  const float* __restrict__ xzb,
                                                  const float* __restrict__ Alog0,
                                                  const float* __restrict__ Alog1,
                                                  const float* __restrict__ D0,
                                                  const float* __restrict__ D1,
                                                  const float* __restrict__ Hini,
                                                  float* __restrict__ y) {
    int gid = blockIdx.x * 256 + threadIdx.x;
    int n = gid & 15;
    int t = gid >> 4;
    int d = t % DM;
    int rem = t / DM;
    int chunk = rem & (NCH - 1);
    int dirb = rem >> 5;
    int b = dirb >> 1, dir = dirb & 1;
    const float* xd = dir ? xd1 : xd0;
    float Av = -__expf((dir ? Alog1 : Alog0)[d * NST + n]);
    float Dv = (dir ? D1 : D0)[d];
    float h = Hini[gid];
    int s0 = chunk * CT;
    int col = dir * DM + d;
#pragma unroll 2
    for (int s = 0; s < CT; s++) {
        int l = dir ? (SEQL - 1 - (s0 + s)) : (s0 + s);
        size_t row = (size_t)(b << 12) + l;
        float dtv = dtb[row * 384 + col];
        float xcv = xcb[row * 384 + col];
        float Bv  = xd[row * XDW + DTR + n];
        float Cv  = xd[row * XDW + DTR + NST + n];
        h = __expf(dtv * Av) * h + dtv * Bv * xcv;
        float p = h * Cv;
        p += __shfl_xor(p, 1); p += __shfl_xor(p, 2);
        p += __shfl_xor(p, 4); p += __shfl_xor(p, 8);
        if (n == 0) {
            float zv = xzb[row * 768 + dir * 384 + DM + d];
            y[row * 384 + col] = (p + Dv * xcv) * siluf(zv);
        }
    }
}

// ---------------- pack [out_w0 | out_w1] -> [192, 384] fp32 ----------------
__global__ void pack_wcat(const float* __restrict__ w0, const float* __restrict__ w1,
                          float* __restrict__ wcat) {
    int idx = blockIdx.x * 256 + threadIdx.x;   // 192*384
    int n = idx / 384, k = idx % 384;
    wcat[idx] = (k < DM) ? w0[n * DM + k] : w1[n * DM + k - DM];
}

// ---------------- depthwise 3x3 (both halves) + SimpleGate ----------------
__global__ __launch_bounds__(256) void dwgate_kernel(const float* __restrict__ t,
                                                     const float* __restrict__ dww,
                                                     const float* __restrict__ dwb,
                                                     float* __restrict__ g) {
    int idx = blockIdx.x * 256 + threadIdx.x;   // BL*384
    int j = idx % 384;
    int row = idx / 384;
    int b = row >> 12, hw = row & 4095;
    int h = hw >> 6, w = hw & 63;
    float a1 = dwb[j], a2 = dwb[j + 384];
#pragma unroll
    for (int dy = -1; dy <= 1; dy++) {
        int hh = h + dy;
        if (hh < 0 || hh >= 64) continue;
#pragma unroll
        for (int dx = -1; dx <= 1; dx++) {
            int ww = w + dx;
            if (ww < 0 || ww >= 64) continue;
            size_t base = ((size_t)(b << 12) + (hh << 6) + ww) * 768;
            int wi = (dy + 1) * 3 + (dx + 1);
            a1 += dww[j * 9 + wi] * t[base + j];
            a2 += dww[(j + 384) * 9 + wi] * t[base + j + 384];
        }
    }
    g[(size_t)row * 384 + j] = a1 * sigf(a2);
}

extern "C" void kernel_launch(void* const* d_in, const int* in_sizes, int n_in,
                              void* d_out, int out_size, void* d_ws, size_t ws_size,
                              hipStream_t stream) {
    const float* x         = (const float*)d_in[0];
    const float* ln_w      = (const float*)d_in[1];
    const float* ln_b      = (const float*)d_in[2];
    const float* scale_mod = (const float*)d_in[3];
    const float* c1w       = (const float*)d_in[4];
    const float* c1b       = (const float*)d_in[5];
    const float* dww       = (const float*)d_in[6];
    const float* dwb       = (const float*)d_in[7];
    const float* c2w       = (const float*)d_in[8];
    const float* c2b       = (const float*)d_in[9];
    const float* gamma     = (const float*)d_in[10];
    const float* in_w0     = (const float*)d_in[11];
    const float* conv_w0   = (const float*)d_in[12];
    const float* conv_b0   = (const float*)d_in[13];
    const float* xproj_w0  = (const float*)d_in[14];
    const float* dt_w0     = (const float*)d_in[15];
    const float* dt_b0     = (const float*)d_in[16];
    const float* A_log0    = (const float*)d_in[17];
    const float* D0        = (const float*)d_in[18];
    const float* out_w0    = (const float*)d_in[19];
    const float* in_w1     = (const float*)d_in[20];
    const float* conv_w1   = (const float*)d_in[21];
    const float* conv_b1   = (const float*)d_in[22];
    const float* xproj_w1  = (const float*)d_in[23];
    const float* dt_w1     = (const float*)d_in[24];
    const float* dt_b1     = (const float*)d_in[25];
    const float* A_log1    = (const float*)d_in[26];
    const float* D1        = (const float*)d_in[27];
    const float* out_w1    = (const float*)d_in[28];

    float* wsf = (float*)d_ws;
    // workspace layout (floats); total ~20.85M floats (~83.4 MB)
    const size_t o_xn  = 0;                         // BL*192
    const size_t o_xz  = o_xn  + (size_t)BLR * DM;  // BL*768 (reused as SGFN t)
    const size_t o_xc  = o_xz  + (size_t)BLR * 768; // BL*384 (reused as SGFN g)
    const size_t o_dt  = o_xc  + (size_t)BLR * 384; // BL*384
    const size_t o_y   = o_dt  + (size_t)BLR * 384; // BL*384
    const size_t o_xm  = o_y   + (size_t)BLR * 384; // BL*192
    const size_t o_xd0 = o_xm  + (size_t)BLR * DM;  // BL*44
    const size_t o_xd1 = o_xd0 + (size_t)BLR * XDW; // BL*44
    const size_t o_S   = o_xd1 + (size_t)BLR * XDW; // 4*NCH*3072
    const size_t o_P   = o_S   + (size_t)4 * NCH * 3072;
    const size_t o_H   = o_P   + (size_t)4 * NCH * 3072;
    const size_t o_wc  = o_H   + (size_t)4 * NCH * 3072; // 192*384 fp32

    // 1. LayerNorm
    ln_kernel<<<BLR / 4, 256, 0, stream>>>(x, ln_w, ln_b, wsf + o_xn);
    // 2-3. in-proj GEMMs (both directions) -> xz [BL,768]
    dim3 gin(6, 128);
    gemm_nt<0><<<gin, 256, 0, stream>>>(wsf + o_xn, DM, in_w0, DM, wsf + o_xz, 768, 384, DM,
                                        nullptr, nullptr, nullptr, nullptr, nullptr);
    gemm_nt<0><<<gin, 256, 0, stream>>>(wsf + o_xn, DM, in_w1, DM, wsf + o_xz + 384, 768, 384, DM,
                                        nullptr, nullptr, nullptr, nullptr, nullptr);
    // 4. depthwise conv4 + SiLU -> xc [BL,384]
    conv_silu_kernel<<<(BLR * 384) / 256, 256, 0, stream>>>(wsf + o_xz, conv_w0, conv_b0,
                                                            conv_w1, conv_b1, wsf + o_xc);
    // 5-6. x-proj GEMMs -> xd [BL,44] per dir
    dim3 gxd(1, 128);
    gemm_nt<0><<<gxd, 256, 0, stream>>>(wsf + o_xc, 384, xproj_w0, DM, wsf + o_xd0, XDW, XDW, DM,
                                        nullptr, nullptr, nullptr, nullptr, nullptr);
    gemm_nt<0><<<gxd, 256, 0, stream>>>(wsf + o_xc + DM, 384, xproj_w1, DM, wsf + o_xd1, XDW, XDW, DM,
                                        nullptr, nullptr, nullptr, nullptr, nullptr);
    // 7-8. dt-proj + softplus -> dt [BL,384]
    dim3 gdt(3, 128);
    gemm_nt<2><<<gdt, 256, 0, stream>>>(wsf + o_xd0, XDW, dt_w0, DTR, wsf + o_dt, 384, DM, DTR,
                                        dt_b0, nullptr, nullptr, nullptr, nullptr);
    gemm_nt<2><<<gdt, 256, 0, stream>>>(wsf + o_xd1, XDW, dt_w1, DTR, wsf + o_dt + DM, 384, DM, DTR,
                                        dt_b1, nullptr, nullptr, nullptr, nullptr);
    // 9-11. chunked selective scan -> y [BL,384]
    scan_partial<<<1536, 256, 0, stream>>>(wsf + o_dt, wsf + o_xc, wsf + o_xd0, wsf + o_xd1,
                                           A_log0, A_log1, wsf + o_S, wsf + o_P);
    scan_combine<<<48, 256, 0, stream>>>(wsf + o_S, wsf + o_P, wsf + o_H);
    scan_final<<<1536, 256, 0, stream>>>(wsf + o_dt, wsf + o_xc, wsf + o_xd0, wsf + o_xd1,
                                         wsf + o_xz, A_log0, A_log1, D0, D1, wsf + o_H, wsf + o_y);
    // 12-13. out-proj (packed K=384) with scale_mod -> xm [BL,192]
    pack_wcat<<<(DM * 384) / 256, 256, 0, stream>>>(out_w0, out_w1, wsf + o_wc);
    gemm_nt<3><<<gdt, 256, 0, stream>>>(wsf + o_y, 384, wsf + o_wc, 384, wsf + o_xm, DM,
                                        DM, 384, nullptr, scale_mod, nullptr, nullptr, nullptr);
    // 14. SGFN conv1x1 #1 -> t (reuses xz region)
    dim3 gs1(12, 128);
    gemm_nt<1><<<gs1, 256, 0, stream>>>(wsf + o_xm, DM, c1w, DM, wsf + o_xz, 768, 768, DM,
                                        c1b, nullptr, nullptr, nullptr, nullptr);
    // 15. depthwise 3x3 + gate -> g (reuses xc region)
    dwgate_kernel<<<(BLR * 384) / 256, 256, 0, stream>>>(wsf + o_xz, dww, dwb, wsf + o_xc);
    // 16. SGFN conv1x1 #2 + final residual -> d_out (fp32, NCHW)
    gemm_nt<4><<<gdt, 256, 0, stream>>>(wsf + o_xc, 384, c2w, 384, wsf + o_y, DM, DM, 384,
                                        c2b, gamma, wsf + o_xm, x, (float*)d_out);
}

// Round 3
// 562.711 us; speedup vs baseline: 1.1278x; 1.1278x over previous
//
#include <hip/hip_runtime.h>
#include <hip/hip_bf16.h>

#define BSZ   2
#define SEQL  4096
#define BLR   8192      // BSZ * SEQL rows
#define DM    192
#define NST   16
#define DTR   12
#define XDW   44        // DTR + 2*NST
#define XDP   48        // padded leading dim for xd (16B-aligned float4 views)
#define NCH   128       // scan chunks
#define CT    32        // chunk length (NCH*CT == SEQL)

__device__ __forceinline__ float sigf(float x) { return 1.f / (1.f + __expf(-x)); }
__device__ __forceinline__ float siluf(float x) { return x * sigf(x); }
__device__ __forceinline__ float softplusf(float x) { return x > 20.f ? x : log1pf(__expf(x)); }

// ---------------- LayerNorm over channels: NCHW fp32 -> [BL,192] fp32 ----------------
__global__ __launch_bounds__(256) void ln_kernel(const float* __restrict__ x,
                                                 const float* __restrict__ lw,
                                                 const float* __restrict__ lb,
                                                 float* __restrict__ xn) {
    int row  = blockIdx.x * 4 + (threadIdx.x >> 6);   // one wave per row
    int lane = threadIdx.x & 63;
    int b = row >> 12, hw = row & 4095;
    float v[3];
#pragma unroll
    for (int i = 0; i < 3; i++) {
        int c = lane + (i << 6);
        v[i] = x[(((size_t)b * DM + c) << 12) + hw];
    }
    float s = v[0] + v[1] + v[2];
    float q = v[0] * v[0] + v[1] * v[1] + v[2] * v[2];
#pragma unroll
    for (int m = 32; m > 0; m >>= 1) { s += __shfl_xor(s, m); q += __shfl_xor(q, m); }
    float mu  = s * (1.f / DM);
    float var = q * (1.f / DM) - mu * mu;
    float rs  = rsqrtf(var + 1e-5f);
#pragma unroll
    for (int i = 0; i < 3; i++) {
        int c = lane + (i << 6);
        xn[(size_t)row * DM + c] = (v[i] - mu) * rs * lw[c] + lb[c];
    }
}

// ---------------- generic NT GEMM: C[m,n] = sum_k A[m,k] * W[n,k]  ----------------
// EPI: 0 plain, 1 +bias, 2 softplus(x+bias), 3 *scalar, 4 final residual (fp32 NCHW out)
template <int EPI>
__global__ __launch_bounds__(256) void gemm_nt(const float* __restrict__ A, int lda,
                                               const float* __restrict__ W, int ldw,
                                               float* __restrict__ C, int ldc,
                                               int N, int K,
                                               const float* __restrict__ bias,
                                               const float* __restrict__ scal,
                                               const float* __restrict__ aux,
                                               const float* __restrict__ xres,
                                               float* __restrict__ outp) {
    __shared__ float As[16][68];
    __shared__ float Ws[16][68];
    const int tid = threadIdx.x;
    const int tx = tid & 15, ty = tid >> 4;
    const int m0 = blockIdx.y << 6, n0 = blockIdx.x << 6;
    float acc[4][4] = {};
    for (int k0 = 0; k0 < K; k0 += 16) {
#pragma unroll
        for (int i = 0; i < 4; i++) {
            int lin = (i << 8) + tid;
            int r = lin >> 4, kk = lin & 15;
            float av = 0.f;
            if (k0 + kk < K) av = A[(size_t)(m0 + r) * lda + k0 + kk];
            As[kk][r] = av;
            float wv = 0.f;
            if (n0 + r < N && k0 + kk < K) wv = W[(size_t)(n0 + r) * ldw + k0 + kk];
            Ws[kk][r] = wv;
        }
        __syncthreads();
#pragma unroll
        for (int k = 0; k < 16; k++) {
            float a_[4], b_[4];
#pragma unroll
            for (int i = 0; i < 4; i++) a_[i] = As[k][(ty << 2) + i];
#pragma unroll
            for (int j = 0; j < 4; j++) b_[j] = Ws[k][(tx << 2) + j];
#pragma unroll
            for (int i = 0; i < 4; i++)
#pragma unroll
                for (int j = 0; j < 4; j++) acc[i][j] += a_[i] * b_[j];
        }
        __syncthreads();
    }
#pragma unroll
    for (int i = 0; i < 4; i++) {
        int m = m0 + (ty << 2) + i;
#pragma unroll
        for (int j = 0; j < 4; j++) {
            int n = n0 + (tx << 2) + j;
            if (n >= N) continue;
            float v = acc[i][j];
            if (EPI == 1) v += bias[n];
            if (EPI == 2) v = softplusf(v + bias[n]);
            if (EPI == 3) v *= scal[0];
            if (EPI == 4) {
                float sg  = v + bias[n];
                int b = m >> 12, hw = m & 4095;
                float xmv = aux[(size_t)m * DM + n];
                size_t oi = (((size_t)b * DM + n) << 12) + hw;
                outp[oi] = xres[oi] + scal[0] * (xmv + sg);
                continue;
            }
            C[(size_t)m * ldc + n] = v;
        }
    }
}

// ---------------- causal (dir0) / anti-causal (dir1) depthwise conv4 + SiLU ----------------
__global__ __launch_bounds__(256) void conv_silu_kernel(const float* __restrict__ xz,
                                                        const float* __restrict__ cw0, const float* __restrict__ cb0,
                                                        const float* __restrict__ cw1, const float* __restrict__ cb1,
                                                        float* __restrict__ xc) {
    int idx = blockIdx.x * 256 + threadIdx.x;   // BL*384
    int col = idx % 384;
    int row = idx / 384;
    int dir = col >= DM;
    int d = col - dir * DM;
    int b = row >> 12, l = row & 4095;
    const float* cw = dir ? cw1 : cw0;
    float acc = (dir ? cb1 : cb0)[d];
#pragma unroll
    for (int k = 0; k < 4; k++) {
        float w = cw[d * 4 + k];
        int ls = dir ? (l + 3 - k) : (l - 3 + k);
        if (ls >= 0 && ls < SEQL)
            acc += w * xz[((size_t)(b << 12) + ls) * 768 + dir * 384 + d];
    }
    xc[(size_t)row * 384 + col] = siluf(acc);
}

// ---------------- chunked scan, pass A: thread=(b,dir,chunk,d), h[16] in regs ----------------
// grid = 4*NCH blocks of 192 threads (lane = d). S/P layout: [(dirb*NCH+chunk)*3072 + d*16 + n]
__global__ __launch_bounds__(192) void scan_partial(const float* __restrict__ dtb,
                                                    const float* __restrict__ xcb,
                                                    const float* __restrict__ xd0,
                                                    const float* __restrict__ xd1,
                                                    const float* __restrict__ Alog0,
                                                    const float* __restrict__ Alog1,
                                                    float* __restrict__ S, float* __restrict__ P) {
    int d = threadIdx.x;
    int blk = blockIdx.x;              // dirb*NCH + chunk
    int chunk = blk & (NCH - 1);
    int dirb = blk >> 7;
    int b = dirb >> 1, dir = dirb & 1;
    const float* xd   = dir ? xd1 : xd0;
    const float* Alog = dir ? Alog1 : Alog0;
    float A[16], h[16];
#pragma unroll
    for (int n = 0; n < 16; n++) { A[n] = -__expf(Alog[d * NST + n]); h[n] = 0.f; }
    float sdt = 0.f;
    int col = dir * DM + d;
    int l0 = chunk * CT;
    for (int s = 0; s < CT; s++) {
        int l = dir ? (SEQL - 1 - (l0 + s)) : (l0 + s);
        size_t row = ((size_t)b << 12) + l;
        float dtv = dtb[row * 384 + col];
        float xcv = xcb[row * 384 + col];
        const float4* Bp = reinterpret_cast<const float4*>(xd + row * XDP + DTR);
        float4 Bq[4] = { Bp[0], Bp[1], Bp[2], Bp[3] };
        const float* Bf = reinterpret_cast<const float*>(Bq);
        float dx = dtv * xcv;
#pragma unroll
        for (int n = 0; n < 16; n++)
            h[n] = __expf(dtv * A[n]) * h[n] + dx * Bf[n];
        sdt += dtv;
    }
    float4* Sp = reinterpret_cast<float4*>(S + (size_t)blk * 3072 + d * 16);
    float4* Pp = reinterpret_cast<float4*>(P + (size_t)blk * 3072 + d * 16);
#pragma unroll
    for (int q = 0; q < 4; q++) {
        Sp[q] = make_float4(h[q * 4], h[q * 4 + 1], h[q * 4 + 2], h[q * 4 + 3]);
        Pp[q] = make_float4(__expf(A[q * 4] * sdt), __expf(A[q * 4 + 1] * sdt),
                            __expf(A[q * 4 + 2] * sdt), __expf(A[q * 4 + 3] * sdt));
    }
}

// ---------------- pass B: sequential combine over chunks, in place (S -> Hini) ----------------
__global__ __launch_bounds__(256) void scan_combine(float* SH, const float* __restrict__ P) {
    int id = blockIdx.x * 256 + threadIdx.x;    // 4*3072
    int dirb = id / 3072;
    int dn = id % 3072;
    float h = 0.f;
#pragma unroll 4
    for (int c = 0; c < NCH; c++) {
        size_t idx = (size_t)(dirb * NCH + c) * 3072 + dn;
        float s = SH[idx], p = P[idx];
        SH[idx] = h;
        h = p * h + s;
    }
}

// ---------------- pass C: replay with true init, fused y = (h.C + D*x)*silu(z) ----------------
__global__ __launch_bounds__(192) void scan_apply(const float* __restrict__ dtb,
                                                  const float* __restrict__ xcb,
                                                  const float* __restrict__ xd0,
                                                  const float* __restrict__ xd1,
                                                  const float* __restrict__ xzb,
                                                  const float* __restrict__ Alog0,
                                                  const float* __restrict__ Alog1,
                                                  const float* __restrict__ D0,
                                                  const float* __restrict__ D1,
                                                  const float* __restrict__ Hini,
                                                  float* __restrict__ y) {
    int d = threadIdx.x;
    int blk = blockIdx.x;
    int chunk = blk & (NCH - 1);
    int dirb = blk >> 7;
    int b = dirb >> 1, dir = dirb & 1;
    const float* xd   = dir ? xd1 : xd0;
    const float* Alog = dir ? Alog1 : Alog0;
    float Dv = (dir ? D1 : D0)[d];
    float A[16], h[16];
#pragma unroll
    for (int n = 0; n < 16; n++) A[n] = -__expf(Alog[d * NST + n]);
    const float4* Hp = reinterpret_cast<const float4*>(Hini + (size_t)blk * 3072 + d * 16);
#pragma unroll
    for (int q = 0; q < 4; q++) {
        float4 hq = Hp[q];
        h[q * 4] = hq.x; h[q * 4 + 1] = hq.y; h[q * 4 + 2] = hq.z; h[q * 4 + 3] = hq.w;
    }
    int col = dir * DM + d;
    int l0 = chunk * CT;
    for (int s = 0; s < CT; s++) {
        int l = dir ? (SEQL - 1 - (l0 + s)) : (l0 + s);
        size_t row = ((size_t)b << 12) + l;
        float dtv = dtb[row * 384 + col];
        float xcv = xcb[row * 384 + col];
        const float4* Bp = reinterpret_cast<const float4*>(xd + row * XDP + DTR);
        const float4* Cp = reinterpret_cast<const float4*>(xd + row * XDP + DTR + NST);
        float4 Bq[4] = { Bp[0], Bp[1], Bp[2], Bp[3] };
        float4 Cq[4] = { Cp[0], Cp[1], Cp[2], Cp[3] };
        const float* Bf = reinterpret_cast<const float*>(Bq);
        const float* Cf = reinterpret_cast<const float*>(Cq);
        float dx = dtv * xcv;
        float p = 0.f;
#pragma unroll
        for (int n = 0; n < 16; n++) {
            h[n] = __expf(dtv * A[n]) * h[n] + dx * Bf[n];
            p += h[n] * Cf[n];
        }
        float zv = xzb[row * 768 + dir * 384 + DM + d];
        y[row * 384 + col] = (p + Dv * xcv) * siluf(zv);
    }
}

// ---------------- pack [out_w0 | out_w1] -> [192, 384] fp32 ----------------
__global__ void pack_wcat(const float* __restrict__ w0, const float* __restrict__ w1,
                          float* __restrict__ wcat) {
    int idx = blockIdx.x * 256 + threadIdx.x;   // 192*384
    int n = idx / 384, k = idx % 384;
    wcat[idx] = (k < DM) ? w0[n * DM + k] : w1[n * DM + k - DM];
}

// ---------------- depthwise 3x3 (both halves) + SimpleGate ----------------
__global__ __launch_bounds__(256) void dwgate_kernel(const float* __restrict__ t,
                                                     const float* __restrict__ dww,
                                                     const float* __restrict__ dwb,
                                                     float* __restrict__ g) {
    int idx = blockIdx.x * 256 + threadIdx.x;   // BL*384
    int j = idx % 384;
    int row = idx / 384;
    int b = row >> 12, hw = row & 4095;
    int h = hw >> 6, w = hw & 63;
    float a1 = dwb[j], a2 = dwb[j + 384];
#pragma unroll
    for (int dy = -1; dy <= 1; dy++) {
        int hh = h + dy;
        if (hh < 0 || hh >= 64) continue;
#pragma unroll
        for (int dx = -1; dx <= 1; dx++) {
            int ww = w + dx;
            if (ww < 0 || ww >= 64) continue;
            size_t base = ((size_t)(b << 12) + (hh << 6) + ww) * 768;
            int wi = (dy + 1) * 3 + (dx + 1);
            a1 += dww[j * 9 + wi] * t[base + j];
            a2 += dww[(j + 384) * 9 + wi] * t[base + j + 384];
        }
    }
    g[(size_t)row * 384 + j] = a1 * sigf(a2);
}

extern "C" void kernel_launch(void* const* d_in, const int* in_sizes, int n_in,
                              void* d_out, int out_size, void* d_ws, size_t ws_size,
                              hipStream_t stream) {
    const float* x         = (const float*)d_in[0];
    const float* ln_w      = (const float*)d_in[1];
    const float* ln_b      = (const float*)d_in[2];
    const float* scale_mod = (const float*)d_in[3];
    const float* c1w       = (const float*)d_in[4];
    const float* c1b       = (const float*)d_in[5];
    const float* dww       = (const float*)d_in[6];
    const float* dwb       = (const float*)d_in[7];
    const float* c2w       = (const float*)d_in[8];
    const float* c2b       = (const float*)d_in[9];
    const float* gamma     = (const float*)d_in[10];
    const float* in_w0     = (const float*)d_in[11];
    const float* conv_w0   = (const float*)d_in[12];
    const float* conv_b0   = (const float*)d_in[13];
    const float* xproj_w0  = (const float*)d_in[14];
    const float* dt_w0     = (const float*)d_in[15];
    const float* dt_b0     = (const float*)d_in[16];
    const float* A_log0    = (const float*)d_in[17];
    const float* D0        = (const float*)d_in[18];
    const float* out_w0    = (const float*)d_in[19];
    const float* in_w1     = (const float*)d_in[20];
    const float* conv_w1   = (const float*)d_in[21];
    const float* conv_b1   = (const float*)d_in[22];
    const float* xproj_w1  = (const float*)d_in[23];
    const float* dt_w1     = (const float*)d_in[24];
    const float* dt_b1     = (const float*)d_in[25];
    const float* A_log1    = (const float*)d_in[26];
    const float* D1        = (const float*)d_in[27];
    const float* out_w1    = (const float*)d_in[28];

    float* wsf = (float*)d_ws;
    // workspace layout (floats), total ~19.73M floats (~78.9 MB)
    const size_t o_xn  = 0;                         // BL*192; dead after in-proj -> reused as S/Hini
    const size_t o_xz  = o_xn  + (size_t)BLR * DM;  // BL*768 (reused as SGFN t)
    const size_t o_xc  = o_xz  + (size_t)BLR * 768; // BL*384 (reused as SGFN g)
    const size_t o_dt  = o_xc  + (size_t)BLR * 384; // BL*384
    const size_t o_y   = o_dt  + (size_t)BLR * 384; // BL*384
    const size_t o_xm  = o_y   + (size_t)BLR * 384; // BL*192; free until out-proj -> reused as P
    const size_t o_xd0 = o_xm  + (size_t)BLR * DM;  // BL*48 (padded)
    const size_t o_xd1 = o_xd0 + (size_t)BLR * XDP; // BL*48
    const size_t o_wc  = o_xd1 + (size_t)BLR * XDP; // 192*384

    float* S_H = wsf + o_xn;   // 4*NCH*3072 = 1.57M floats == BL*192 exactly
    float* Pb  = wsf + o_xm;   // same size

    // 1. LayerNorm
    ln_kernel<<<BLR / 4, 256, 0, stream>>>(x, ln_w, ln_b, wsf + o_xn);
    // 2-3. in-proj GEMMs (both directions) -> xz [BL,768]
    dim3 gin(6, 128);
    gemm_nt<0><<<gin, 256, 0, stream>>>(wsf + o_xn, DM, in_w0, DM, wsf + o_xz, 768, 384, DM,
                                        nullptr, nullptr, nullptr, nullptr, nullptr);
    gemm_nt<0><<<gin, 256, 0, stream>>>(wsf + o_xn, DM, in_w1, DM, wsf + o_xz + 384, 768, 384, DM,
                                        nullptr, nullptr, nullptr, nullptr, nullptr);
    // 4. depthwise conv4 + SiLU -> xc [BL,384]
    conv_silu_kernel<<<(BLR * 384) / 256, 256, 0, stream>>>(wsf + o_xz, conv_w0, conv_b0,
                                                            conv_w1, conv_b1, wsf + o_xc);
    // 5-6. x-proj GEMMs -> xd [BL,48pad] per dir
    dim3 gxd(1, 128);
    gemm_nt<0><<<gxd, 256, 0, stream>>>(wsf + o_xc, 384, xproj_w0, DM, wsf + o_xd0, XDP, XDW, DM,
                                        nullptr, nullptr, nullptr, nullptr, nullptr);
    gemm_nt<0><<<gxd, 256, 0, stream>>>(wsf + o_xc + DM, 384, xproj_w1, DM, wsf + o_xd1, XDP, XDW, DM,
                                        nullptr, nullptr, nullptr, nullptr, nullptr);
    // 7-8. dt-proj + softplus -> dt [BL,384]
    dim3 gdt(3, 128);
    gemm_nt<2><<<gdt, 256, 0, stream>>>(wsf + o_xd0, XDP, dt_w0, DTR, wsf + o_dt, 384, DM, DTR,
                                        dt_b0, nullptr, nullptr, nullptr, nullptr);
    gemm_nt<2><<<gdt, 256, 0, stream>>>(wsf + o_xd1, XDP, dt_w1, DTR, wsf + o_dt + DM, 384, DM, DTR,
                                        dt_b1, nullptr, nullptr, nullptr, nullptr);
    // 9-11. chunked selective scan -> y [BL,384]
    scan_partial<<<4 * NCH, 192, 0, stream>>>(wsf + o_dt, wsf + o_xc, wsf + o_xd0, wsf + o_xd1,
                                              A_log0, A_log1, S_H, Pb);
    scan_combine<<<48, 256, 0, stream>>>(S_H, Pb);
    scan_apply<<<4 * NCH, 192, 0, stream>>>(wsf + o_dt, wsf + o_xc, wsf + o_xd0, wsf + o_xd1,
                                            wsf + o_xz, A_log0, A_log1, D0, D1, S_H, wsf + o_y);
    // 12-13. out-proj (packed K=384) with scale_mod -> xm [BL,192]
    pack_wcat<<<(DM * 384) / 256, 256, 0, stream>>>(out_w0, out_w1, wsf + o_wc);
    gemm_nt<3><<<gdt, 256, 0, stream>>>(wsf + o_y, 384, wsf + o_wc, 384, wsf + o_xm, DM,
                                        DM, 384, nullptr, scale_mod, nullptr, nullptr, nullptr);
    // 14. SGFN conv1x1 #1 -> t (reuses xz region)
    dim3 gs1(12, 128);
    gemm_nt<1><<<gs1, 256, 0, stream>>>(wsf + o_xm, DM, c1w, DM, wsf + o_xz, 768, 768, DM,
                                        c1b, nullptr, nullptr, nullptr, nullptr);
    // 15. depthwise 3x3 + gate -> g (reuses xc region)
    dwgate_kernel<<<(BLR * 384) / 256, 256, 0, stream>>>(wsf + o_xz, dww, dwb, wsf + o_xc);
    // 16. SGFN conv1x1 #2 + final residual -> d_out (fp32, NCHW)
    gemm_nt<4><<<gdt, 256, 0, stream>>>(wsf + o_xc, 384, c2w, 384, wsf + o_y, DM, DM, 384,
                                        c2b, gamma, wsf + o_xm, x, (float*)d_out);
}

// Round 4
// 368.454 us; speedup vs baseline: 1.7225x; 1.5272x over previous
//
#include <hip/hip_runtime.h>
#include <hip/hip_bf16.h>

#define BSZ   2
#define SEQL  4096
#define BLR   8192      // BSZ * SEQL rows
#define DM    192
#define NST   16
#define DTR   12
#define XDW   44        // DTR + 2*NST
#define XDP   48        // padded leading dim for xd (16B-aligned float4 views)
#define NCH   128       // scan chunks
#define CT    32        // chunk length (NCH*CT == SEQL)

typedef float f32x4 __attribute__((ext_vector_type(4)));
typedef __bf16 bf16x8 __attribute__((ext_vector_type(8)));

__device__ __forceinline__ float sigf(float x) { return 1.f / (1.f + __expf(-x)); }
__device__ __forceinline__ float siluf(float x) { return x * sigf(x); }
__device__ __forceinline__ float softplusf(float x) { return x > 20.f ? x : log1pf(__expf(x)); }

// ---------------- LayerNorm over channels: NCHW fp32 -> [BL,192] fp32 ----------------
__global__ __launch_bounds__(256) void ln_kernel(const float* __restrict__ x,
                                                 const float* __restrict__ lw,
                                                 const float* __restrict__ lb,
                                                 float* __restrict__ xn) {
    int row  = blockIdx.x * 4 + (threadIdx.x >> 6);   // one wave per row
    int lane = threadIdx.x & 63;
    int b = row >> 12, hw = row & 4095;
    float v[3];
#pragma unroll
    for (int i = 0; i < 3; i++) {
        int c = lane + (i << 6);
        v[i] = x[(((size_t)b * DM + c) << 12) + hw];
    }
    float s = v[0] + v[1] + v[2];
    float q = v[0] * v[0] + v[1] * v[1] + v[2] * v[2];
#pragma unroll
    for (int m = 32; m > 0; m >>= 1) { s += __shfl_xor(s, m); q += __shfl_xor(q, m); }
    float mu  = s * (1.f / DM);
    float var = q * (1.f / DM) - mu * mu;
    float rs  = rsqrtf(var + 1e-5f);
#pragma unroll
    for (int i = 0; i < 3; i++) {
        int c = lane + (i << 6);
        xn[(size_t)row * DM + c] = (v[i] - mu) * rs * lw[c] + lb[c];
    }
}

// ---------------- MFMA bf16 NT GEMM: C[m,n] = sum_k A[m,k] * W[n,k] ----------------
// A,W fp32 in memory, converted to bf16 at LDS staging; fp32 accumulate.
// 64x64 tile, BK=32, 4 waves each 32x32 via 2x2 mfma_f32_16x16x32_bf16.
// EPI: 0 plain, 1 +bias, 2 softplus(x+bias), 3 *scalar, 4 final residual (fp32 NCHW out)
template <int EPI>
__global__ __launch_bounds__(256) void gemm_mfma(const float* __restrict__ A, int lda,
                                                 const float* __restrict__ W, int ldw,
                                                 float* __restrict__ C, int ldc,
                                                 int N, int K,
                                                 const float* __restrict__ bias,
                                                 const float* __restrict__ scal,
                                                 const float* __restrict__ aux,
                                                 const float* __restrict__ xres,
                                                 float* __restrict__ outp) {
    __shared__ __bf16 As[64][40];   // row pad 40 (80 B): 16B-aligned, <=2-way bank alias
    __shared__ __bf16 Ws[64][40];
    const int tid  = threadIdx.x;
    const int wave = tid >> 6, lane = tid & 63;
    const int ko = lane >> 4, lm = lane & 15;
    const int wm = (wave & 1) * 32, wn = (wave >> 1) * 32;
    const int m0 = blockIdx.y << 6, n0 = blockIdx.x << 6;
    const int r = tid >> 2, cq = (tid & 3) * 8;     // staging: 64 rows x 32 cols, 8 floats/thread
    f32x4 acc[2][2] = {};

    for (int k0 = 0; k0 < K; k0 += 32) {
        // ---- stage A tile [64][32] ----
        {
            bf16x8 pk;
            if (k0 + 32 <= K) {
                const float4* ap = reinterpret_cast<const float4*>(A + (size_t)(m0 + r) * lda + k0 + cq);
                float4 a0 = ap[0], a1 = ap[1];
                pk[0] = (__bf16)a0.x; pk[1] = (__bf16)a0.y; pk[2] = (__bf16)a0.z; pk[3] = (__bf16)a0.w;
                pk[4] = (__bf16)a1.x; pk[5] = (__bf16)a1.y; pk[6] = (__bf16)a1.z; pk[7] = (__bf16)a1.w;
            } else {
#pragma unroll
                for (int j = 0; j < 8; j++) {
                    int k = k0 + cq + j;
                    pk[j] = (__bf16)((k < K) ? A[(size_t)(m0 + r) * lda + k] : 0.f);
                }
            }
            *reinterpret_cast<bf16x8*>(&As[r][cq]) = pk;
        }
        // ---- stage W tile [64][32] ----
        {
            bf16x8 pk;
            if (n0 + r < N && k0 + 32 <= K) {
                const float4* wp = reinterpret_cast<const float4*>(W + (size_t)(n0 + r) * ldw + k0 + cq);
                float4 w0 = wp[0], w1 = wp[1];
                pk[0] = (__bf16)w0.x; pk[1] = (__bf16)w0.y; pk[2] = (__bf16)w0.z; pk[3] = (__bf16)w0.w;
                pk[4] = (__bf16)w1.x; pk[5] = (__bf16)w1.y; pk[6] = (__bf16)w1.z; pk[7] = (__bf16)w1.w;
            } else {
#pragma unroll
                for (int j = 0; j < 8; j++) {
                    int k = k0 + cq + j;
                    pk[j] = (__bf16)((n0 + r < N && k < K) ? W[(size_t)(n0 + r) * ldw + k] : 0.f);
                }
            }
            *reinterpret_cast<bf16x8*>(&Ws[r][cq]) = pk;
        }
        __syncthreads();
        bf16x8 af[2], bfr[2];
#pragma unroll
        for (int ti = 0; ti < 2; ti++)
            af[ti] = *reinterpret_cast<bf16x8*>(&As[wm + ti * 16 + lm][ko * 8]);
#pragma unroll
        for (int tj = 0; tj < 2; tj++)
            bfr[tj] = *reinterpret_cast<bf16x8*>(&Ws[wn + tj * 16 + lm][ko * 8]);
#pragma unroll
        for (int ti = 0; ti < 2; ti++)
#pragma unroll
            for (int tj = 0; tj < 2; tj++)
                acc[ti][tj] = __builtin_amdgcn_mfma_f32_16x16x32_bf16(af[ti], bfr[tj], acc[ti][tj], 0, 0, 0);
        __syncthreads();
    }

    if constexpr (EPI == 4) {
        // add aux (xm, same [m,n] layout) in MFMA layout, transpose via LDS,
        // then hw-coalesced NCHW store of x + gamma*(xm + sg)
        __shared__ float Cs[64][65];
#pragma unroll
        for (int ti = 0; ti < 2; ti++)
#pragma unroll
            for (int tj = 0; tj < 2; tj++) {
                int nn = n0 + wn + tj * 16 + lm;
#pragma unroll
                for (int reg = 0; reg < 4; reg++) {
                    int m = m0 + wm + ti * 16 + ko * 4 + reg;
                    float v = acc[ti][tj][reg];
                    if (nn < N) v += aux[(size_t)m * DM + nn];
                    Cs[wm + ti * 16 + ko * 4 + reg][wn + tj * 16 + lm] = v;
                }
            }
        __syncthreads();
        float g = scal[0];
#pragma unroll
        for (int rep = 0; rep < 16; rep++) {
            int idx = rep * 256 + tid;
            int n = idx >> 6, mi = idx & 63;
            int nn = n0 + n;
            if (nn >= N) continue;
            int m = m0 + mi;
            int b = m >> 12, hw = m & 4095;
            size_t oi = (((size_t)b * DM + nn) << 12) + hw;
            outp[oi] = xres[oi] + g * (Cs[mi][n] + bias[nn]);
        }
        return;
    }

#pragma unroll
    for (int ti = 0; ti < 2; ti++)
#pragma unroll
        for (int tj = 0; tj < 2; tj++) {
            int n = n0 + wn + tj * 16 + lm;
            if (n >= N) continue;
#pragma unroll
            for (int reg = 0; reg < 4; reg++) {
                int m = m0 + wm + ti * 16 + ko * 4 + reg;
                float v = acc[ti][tj][reg];
                if (EPI == 1) v += bias[n];
                if (EPI == 2) v = softplusf(v + bias[n]);
                if (EPI == 3) v *= scal[0];
                C[(size_t)m * ldc + n] = v;
            }
        }
}

// ---------------- causal (dir0) / anti-causal (dir1) depthwise conv4 + SiLU ----------------
__global__ __launch_bounds__(256) void conv_silu_kernel(const float* __restrict__ xz,
                                                        const float* __restrict__ cw0, const float* __restrict__ cb0,
                                                        const float* __restrict__ cw1, const float* __restrict__ cb1,
                                                        float* __restrict__ xc) {
    int idx = blockIdx.x * 256 + threadIdx.x;   // BL*384
    int col = idx % 384;
    int row = idx / 384;
    int dir = col >= DM;
    int d = col - dir * DM;
    int b = row >> 12, l = row & 4095;
    const float* cw = dir ? cw1 : cw0;
    float acc = (dir ? cb1 : cb0)[d];
#pragma unroll
    for (int k = 0; k < 4; k++) {
        float w = cw[d * 4 + k];
        int ls = dir ? (l + 3 - k) : (l - 3 + k);
        if (ls >= 0 && ls < SEQL)
            acc += w * xz[((size_t)(b << 12) + ls) * 768 + dir * 384 + d];
    }
    xc[(size_t)row * 384 + col] = siluf(acc);
}

// ---------------- chunked scan, pass A: thread=(b,dir,chunk,d), h[16] in regs ----------------
__global__ __launch_bounds__(192) void scan_partial(const float* __restrict__ dtb,
                                                    const float* __restrict__ xcb,
                                                    const float* __restrict__ xd0,
                                                    const float* __restrict__ xd1,
                                                    const float* __restrict__ Alog0,
                                                    const float* __restrict__ Alog1,
                                                    float* __restrict__ S, float* __restrict__ P) {
    int d = threadIdx.x;
    int blk = blockIdx.x;              // dirb*NCH + chunk
    int chunk = blk & (NCH - 1);
    int dirb = blk >> 7;
    int b = dirb >> 1, dir = dirb & 1;
    const float* xd   = dir ? xd1 : xd0;
    const float* Alog = dir ? Alog1 : Alog0;
    float A[16], h[16];
#pragma unroll
    for (int n = 0; n < 16; n++) { A[n] = -__expf(Alog[d * NST + n]); h[n] = 0.f; }
    float sdt = 0.f;
    int col = dir * DM + d;
    int l0 = chunk * CT;
    for (int s = 0; s < CT; s++) {
        int l = dir ? (SEQL - 1 - (l0 + s)) : (l0 + s);
        size_t row = ((size_t)b << 12) + l;
        float dtv = dtb[row * 384 + col];
        float xcv = xcb[row * 384 + col];
        const float4* Bp = reinterpret_cast<const float4*>(xd + row * XDP + DTR);
        float4 Bq[4] = { Bp[0], Bp[1], Bp[2], Bp[3] };
        const float* Bf = reinterpret_cast<const float*>(Bq);
        float dx = dtv * xcv;
#pragma unroll
        for (int n = 0; n < 16; n++)
            h[n] = __expf(dtv * A[n]) * h[n] + dx * Bf[n];
        sdt += dtv;
    }
    float4* Sp = reinterpret_cast<float4*>(S + (size_t)blk * 3072 + d * 16);
    float4* Pp = reinterpret_cast<float4*>(P + (size_t)blk * 3072 + d * 16);
#pragma unroll
    for (int q = 0; q < 4; q++) {
        Sp[q] = make_float4(h[q * 4], h[q * 4 + 1], h[q * 4 + 2], h[q * 4 + 3]);
        Pp[q] = make_float4(__expf(A[q * 4] * sdt), __expf(A[q * 4 + 1] * sdt),
                            __expf(A[q * 4 + 2] * sdt), __expf(A[q * 4 + 3] * sdt));
    }
}

// ---------------- pass B: sequential combine over chunks, in place (S -> Hini) ----------------
__global__ __launch_bounds__(256) void scan_combine(float* SH, const float* __restrict__ P) {
    int id = blockIdx.x * 256 + threadIdx.x;    // 4*3072
    int dirb = id / 3072;
    int dn = id % 3072;
    float h = 0.f;
#pragma unroll 4
    for (int c = 0; c < NCH; c++) {
        size_t idx = (size_t)(dirb * NCH + c) * 3072 + dn;
        float s = SH[idx], p = P[idx];
        SH[idx] = h;
        h = p * h + s;
    }
}

// ---------------- pass C: replay with true init, fused y = (h.C + D*x)*silu(z) ----------------
__global__ __launch_bounds__(192) void scan_apply(const float* __restrict__ dtb,
                                                  const float* __restrict__ xcb,
                                                  const float* __restrict__ xd0,
                                                  const float* __restrict__ xd1,
                                                  const float* __restrict__ xzb,
                                                  const float* __restrict__ Alog0,
                                                  const float* __restrict__ Alog1,
                                                  const float* __restrict__ D0,
                                                  const float* __restrict__ D1,
                                                  const float* __restrict__ Hini,
                                                  float* __restrict__ y) {
    int d = threadIdx.x;
    int blk = blockIdx.x;
    int chunk = blk & (NCH - 1);
    int dirb = blk >> 7;
    int b = dirb >> 1, dir = dirb & 1;
    const float* xd   = dir ? xd1 : xd0;
    const float* Alog = dir ? Alog1 : Alog0;
    float Dv = (dir ? D1 : D0)[d];
    float A[16], h[16];
#pragma unroll
    for (int n = 0; n < 16; n++) A[n] = -__expf(Alog[d * NST + n]);
    const float4* Hp = reinterpret_cast<const float4*>(Hini + (size_t)blk * 3072 + d * 16);
#pragma unroll
    for (int q = 0; q < 4; q++) {
        float4 hq = Hp[q];
        h[q * 4] = hq.x; h[q * 4 + 1] = hq.y; h[q * 4 + 2] = hq.z; h[q * 4 + 3] = hq.w;
    }
    int col = dir * DM + d;
    int l0 = chunk * CT;
    for (int s = 0; s < CT; s++) {
        int l = dir ? (SEQL - 1 - (l0 + s)) : (l0 + s);
        size_t row = ((size_t)b << 12) + l;
        float dtv = dtb[row * 384 + col];
        float xcv = xcb[row * 384 + col];
        const float4* Bp = reinterpret_cast<const float4*>(xd + row * XDP + DTR);
        const float4* Cp = reinterpret_cast<const float4*>(xd + row * XDP + DTR + NST);
        float4 Bq[4] = { Bp[0], Bp[1], Bp[2], Bp[3] };
        float4 Cq[4] = { Cp[0], Cp[1], Cp[2], Cp[3] };
        const float* Bf = reinterpret_cast<const float*>(Bq);
        const float* Cf = reinterpret_cast<const float*>(Cq);
        float dx = dtv * xcv;
        float p = 0.f;
#pragma unroll
        for (int n = 0; n < 16; n++) {
            h[n] = __expf(dtv * A[n]) * h[n] + dx * Bf[n];
            p += h[n] * Cf[n];
        }
        float zv = xzb[row * 768 + dir * 384 + DM + d];
        y[row * 384 + col] = (p + Dv * xcv) * siluf(zv);
    }
}

// ---------------- pack [in_w0; in_w1] -> [768,192] and [out_w0 | out_w1] -> [192,384] ----------------
#define PK_IN  (768 * 192)
#define PK_OUT (192 * 384)
__global__ void pack_weights(const float* __restrict__ iw0, const float* __restrict__ iw1,
                             const float* __restrict__ ow0, const float* __restrict__ ow1,
                             float* __restrict__ win, float* __restrict__ wcat) {
    int idx = blockIdx.x * 256 + threadIdx.x;
    if (idx < PK_IN) {
        win[idx] = (idx < 384 * 192) ? iw0[idx] : iw1[idx - 384 * 192];
    } else if (idx < PK_IN + PK_OUT) {
        int j = idx - PK_IN;
        int n = j / 384, k = j % 384;
        wcat[j] = (k < DM) ? ow0[n * DM + k] : ow1[n * DM + k - DM];
    }
}

// ---------------- depthwise 3x3 (both halves) + SimpleGate ----------------
__global__ __launch_bounds__(256) void dwgate_kernel(const float* __restrict__ t,
                                                     const float* __restrict__ dww,
                                                     const float* __restrict__ dwb,
                                                     float* __restrict__ g) {
    int idx = blockIdx.x * 256 + threadIdx.x;   // BL*384
    int j = idx % 384;
    int row = idx / 384;
    int b = row >> 12, hw = row & 4095;
    int h = hw >> 6, w = hw & 63;
    float a1 = dwb[j], a2 = dwb[j + 384];
#pragma unroll
    for (int dy = -1; dy <= 1; dy++) {
        int hh = h + dy;
        if (hh < 0 || hh >= 64) continue;
#pragma unroll
        for (int dx = -1; dx <= 1; dx++) {
            int ww = w + dx;
            if (ww < 0 || ww >= 64) continue;
            size_t base = ((size_t)(b << 12) + (hh << 6) + ww) * 768;
            int wi = (dy + 1) * 3 + (dx + 1);
            a1 += dww[j * 9 + wi] * t[base + j];
            a2 += dww[(j + 384) * 9 + wi] * t[base + j + 384];
        }
    }
    g[(size_t)row * 384 + j] = a1 * sigf(a2);
}

extern "C" void kernel_launch(void* const* d_in, const int* in_sizes, int n_in,
                              void* d_out, int out_size, void* d_ws, size_t ws_size,
                              hipStream_t stream) {
    const float* x         = (const float*)d_in[0];
    const float* ln_w      = (const float*)d_in[1];
    const float* ln_b      = (const float*)d_in[2];
    const float* scale_mod = (const float*)d_in[3];
    const float* c1w       = (const float*)d_in[4];
    const float* c1b       = (const float*)d_in[5];
    const float* dww       = (const float*)d_in[6];
    const float* dwb       = (const float*)d_in[7];
    const float* c2w       = (const float*)d_in[8];
    const float* c2b       = (const float*)d_in[9];
    const float* gamma     = (const float*)d_in[10];
    const float* in_w0     = (const float*)d_in[11];
    const float* conv_w0   = (const float*)d_in[12];
    const float* conv_b0   = (const float*)d_in[13];
    const float* xproj_w0  = (const float*)d_in[14];
    const float* dt_w0     = (const float*)d_in[15];
    const float* dt_b0     = (const float*)d_in[16];
    const float* A_log0    = (const float*)d_in[17];
    const float* D0        = (const float*)d_in[18];
    const float* out_w0    = (const float*)d_in[19];
    const float* in_w1     = (const float*)d_in[20];
    const float* conv_w1   = (const float*)d_in[21];
    const float* conv_b1   = (const float*)d_in[22];
    const float* xproj_w1  = (const float*)d_in[23];
    const float* dt_w1     = (const float*)d_in[24];
    const float* dt_b1     = (const float*)d_in[25];
    const float* A_log1    = (const float*)d_in[26];
    const float* D1        = (const float*)d_in[27];
    const float* out_w1    = (const float*)d_in[28];

    float* wsf = (float*)d_ws;
    // workspace layout (floats), total ~19.88M floats (~79.5 MB)
    const size_t o_xn  = 0;                         // BL*192; dead after in-proj -> reused as S/Hini
    const size_t o_xz  = o_xn  + (size_t)BLR * DM;  // BL*768 (reused as SGFN t)
    const size_t o_xc  = o_xz  + (size_t)BLR * 768; // BL*384 (reused as SGFN g)
    const size_t o_dt  = o_xc  + (size_t)BLR * 384; // BL*384
    const size_t o_y   = o_dt  + (size_t)BLR * 384; // BL*384
    const size_t o_xm  = o_y   + (size_t)BLR * 384; // BL*192; free until out-proj -> reused as P
    const size_t o_xd0 = o_xm  + (size_t)BLR * DM;  // BL*48 (padded)
    const size_t o_xd1 = o_xd0 + (size_t)BLR * XDP; // BL*48
    const size_t o_wc  = o_xd1 + (size_t)BLR * XDP; // 192*384
    const size_t o_wi  = o_wc  + (size_t)DM * 384;  // 768*192

    float* S_H = wsf + o_xn;   // 4*NCH*3072 = 1.57M floats == BL*192 exactly
    float* Pb  = wsf + o_xm;   // same size

    // 1. LayerNorm
    ln_kernel<<<BLR / 4, 256, 0, stream>>>(x, ln_w, ln_b, wsf + o_xn);
    // 2. pack weights (in-proj concat rows; out-proj concat cols)
    pack_weights<<<(PK_IN + PK_OUT + 255) / 256, 256, 0, stream>>>(in_w0, in_w1, out_w0, out_w1,
                                                                   wsf + o_wi, wsf + o_wc);
    // 3. merged in-proj GEMM (both dirs) -> xz [BL, 768]
    gemm_mfma<0><<<dim3(12, 128), 256, 0, stream>>>(wsf + o_xn, DM, wsf + o_wi, DM, wsf + o_xz, 768,
                                                    768, DM, nullptr, nullptr, nullptr, nullptr, nullptr);
    // 4. depthwise conv4 + SiLU -> xc [BL,384]
    conv_silu_kernel<<<(BLR * 384) / 256, 256, 0, stream>>>(wsf + o_xz, conv_w0, conv_b0,
                                                            conv_w1, conv_b1, wsf + o_xc);
    // 5-6. x-proj GEMMs -> xd [BL,48pad] per dir
    gemm_mfma<0><<<dim3(1, 128), 256, 0, stream>>>(wsf + o_xc, 384, xproj_w0, DM, wsf + o_xd0, XDP,
                                                   XDW, DM, nullptr, nullptr, nullptr, nullptr, nullptr);
    gemm_mfma<0><<<dim3(1, 128), 256, 0, stream>>>(wsf + o_xc + DM, 384, xproj_w1, DM, wsf + o_xd1, XDP,
                                                   XDW, DM, nullptr, nullptr, nullptr, nullptr, nullptr);
    // 7-8. dt-proj + softplus -> dt [BL,384]
    gemm_mfma<2><<<dim3(3, 128), 256, 0, stream>>>(wsf + o_xd0, XDP, dt_w0, DTR, wsf + o_dt, 384,
                                                   DM, DTR, dt_b0, nullptr, nullptr, nullptr, nullptr);
    gemm_mfma<2><<<dim3(3, 128), 256, 0, stream>>>(wsf + o_xd1, XDP, dt_w1, DTR, wsf + o_dt + DM, 384,
                                                   DM, DTR, dt_b1, nullptr, nullptr, nullptr, nullptr);
    // 9-11. chunked selective scan -> y [BL,384]
    scan_partial<<<4 * NCH, 192, 0, stream>>>(wsf + o_dt, wsf + o_xc, wsf + o_xd0, wsf + o_xd1,
                                              A_log0, A_log1, S_H, Pb);
    scan_combine<<<48, 256, 0, stream>>>(S_H, Pb);
    scan_apply<<<4 * NCH, 192, 0, stream>>>(wsf + o_dt, wsf + o_xc, wsf + o_xd0, wsf + o_xd1,
                                            wsf + o_xz, A_log0, A_log1, D0, D1, S_H, wsf + o_y);
    // 12. out-proj (packed K=384) with scale_mod -> xm [BL,192]
    gemm_mfma<3><<<dim3(3, 128), 256, 0, stream>>>(wsf + o_y, 384, wsf + o_wc, 384, wsf + o_xm, DM,
                                                   DM, 384, nullptr, scale_mod, nullptr, nullptr, nullptr);
    // 13. SGFN conv1x1 #1 -> t (reuses xz region)
    gemm_mfma<1><<<dim3(12, 128), 256, 0, stream>>>(wsf + o_xm, DM, c1w, DM, wsf + o_xz, 768,
                                                    768, DM, c1b, nullptr, nullptr, nullptr, nullptr);
    // 14. depthwise 3x3 + gate -> g (reuses xc region)
    dwgate_kernel<<<(BLR * 384) / 256, 256, 0, stream>>>(wsf + o_xz, dww, dwb, wsf + o_xc);
    // 15. SGFN conv1x1 #2 + final residual -> d_out (fp32, NCHW)
    gemm_mfma<4><<<dim3(3, 128), 256, 0, stream>>>(wsf + o_xc, 384, c2w, 384, wsf + o_y, DM,
                                                   DM, 384, c2b, gamma, wsf + o_xm, x, (float*)d_out);
}

// Round 5
// 319.002 us; speedup vs baseline: 1.9895x; 1.1550x over previous
//
#include <hip/hip_runtime.h>
#include <hip/hip_bf16.h>

#define BSZ   2
#define SEQL  4096
#define BLR   8192      // BSZ * SEQL rows
#define DM    192
#define NST   16
#define DTR   12
#define XDW   44        // DTR + 2*NST
#define XDP   48        // padded leading dim for xd (16B-aligned float4 views)
#define NCH   128       // scan chunks
#define CT    32        // chunk length (NCH*CT == SEQL)

typedef float f32x4 __attribute__((ext_vector_type(4)));
typedef __bf16 bf16x8 __attribute__((ext_vector_type(8)));

__device__ __forceinline__ float sigf(float x) { return 1.f / (1.f + __expf(-x)); }
__device__ __forceinline__ float siluf(float x) { return x * sigf(x); }
__device__ __forceinline__ float softplusf(float x) { return x > 20.f ? x : log1pf(__expf(x)); }

// ---------------- LayerNorm over channels: NCHW fp32 -> [BL,192] fp32 ----------------
__global__ __launch_bounds__(256) void ln_kernel(const float* __restrict__ x,
                                                 const float* __restrict__ lw,
                                                 const float* __restrict__ lb,
                                                 float* __restrict__ xn) {
    int row  = blockIdx.x * 4 + (threadIdx.x >> 6);   // one wave per row
    int lane = threadIdx.x & 63;
    int b = row >> 12, hw = row & 4095;
    float v[3];
#pragma unroll
    for (int i = 0; i < 3; i++) {
        int c = lane + (i << 6);
        v[i] = x[(((size_t)b * DM + c) << 12) + hw];
    }
    float s = v[0] + v[1] + v[2];
    float q = v[0] * v[0] + v[1] * v[1] + v[2] * v[2];
#pragma unroll
    for (int m = 32; m > 0; m >>= 1) { s += __shfl_xor(s, m); q += __shfl_xor(q, m); }
    float mu  = s * (1.f / DM);
    float var = q * (1.f / DM) - mu * mu;
    float rs  = rsqrtf(var + 1e-5f);
#pragma unroll
    for (int i = 0; i < 3; i++) {
        int c = lane + (i << 6);
        xn[(size_t)row * DM + c] = (v[i] - mu) * rs * lw[c] + lb[c];
    }
}

// ---------------- MFMA bf16 NT GEMM: C[m,n] = sum_k A[m,k] * W[n,k] ----------------
// EPI: 0 plain, 1 +bias, 2 softplus(x+bias), 3 *scalar, 4 final residual (fp32 NCHW out)
template <int EPI>
__global__ __launch_bounds__(256) void gemm_mfma(const float* __restrict__ A, int lda,
                                                 const float* __restrict__ W, int ldw,
                                                 float* __restrict__ C, int ldc,
                                                 int N, int K,
                                                 const float* __restrict__ bias,
                                                 const float* __restrict__ scal,
                                                 const float* __restrict__ aux,
                                                 const float* __restrict__ xres,
                                                 float* __restrict__ outp) {
    __shared__ __bf16 As[64][40];   // row pad 40 (80 B): 16B-aligned, <=2-way bank alias
    __shared__ __bf16 Ws[64][40];
    const int tid  = threadIdx.x;
    const int wave = tid >> 6, lane = tid & 63;
    const int ko = lane >> 4, lm = lane & 15;
    const int wm = (wave & 1) * 32, wn = (wave >> 1) * 32;
    const int m0 = blockIdx.y << 6, n0 = blockIdx.x << 6;
    const int r = tid >> 2, cq = (tid & 3) * 8;     // staging: 64 rows x 32 cols, 8 floats/thread
    f32x4 acc[2][2] = {};

    for (int k0 = 0; k0 < K; k0 += 32) {
        // ---- stage A tile [64][32] ----
        {
            bf16x8 pk;
            if (k0 + 32 <= K) {
                const float4* ap = reinterpret_cast<const float4*>(A + (size_t)(m0 + r) * lda + k0 + cq);
                float4 a0 = ap[0], a1 = ap[1];
                pk[0] = (__bf16)a0.x; pk[1] = (__bf16)a0.y; pk[2] = (__bf16)a0.z; pk[3] = (__bf16)a0.w;
                pk[4] = (__bf16)a1.x; pk[5] = (__bf16)a1.y; pk[6] = (__bf16)a1.z; pk[7] = (__bf16)a1.w;
            } else {
#pragma unroll
                for (int j = 0; j < 8; j++) {
                    int k = k0 + cq + j;
                    pk[j] = (__bf16)((k < K) ? A[(size_t)(m0 + r) * lda + k] : 0.f);
                }
            }
            *reinterpret_cast<bf16x8*>(&As[r][cq]) = pk;
        }
        // ---- stage W tile [64][32] ----
        {
            bf16x8 pk;
            if (n0 + r < N && k0 + 32 <= K) {
                const float4* wp = reinterpret_cast<const float4*>(W + (size_t)(n0 + r) * ldw + k0 + cq);
                float4 w0 = wp[0], w1 = wp[1];
                pk[0] = (__bf16)w0.x; pk[1] = (__bf16)w0.y; pk[2] = (__bf16)w0.z; pk[3] = (__bf16)w0.w;
                pk[4] = (__bf16)w1.x; pk[5] = (__bf16)w1.y; pk[6] = (__bf16)w1.z; pk[7] = (__bf16)w1.w;
            } else {
#pragma unroll
                for (int j = 0; j < 8; j++) {
                    int k = k0 + cq + j;
                    pk[j] = (__bf16)((n0 + r < N && k < K) ? W[(size_t)(n0 + r) * ldw + k] : 0.f);
                }
            }
            *reinterpret_cast<bf16x8*>(&Ws[r][cq]) = pk;
        }
        __syncthreads();
        bf16x8 af[2], bfr[2];
#pragma unroll
        for (int ti = 0; ti < 2; ti++)
            af[ti] = *reinterpret_cast<bf16x8*>(&As[wm + ti * 16 + lm][ko * 8]);
#pragma unroll
        for (int tj = 0; tj < 2; tj++)
            bfr[tj] = *reinterpret_cast<bf16x8*>(&Ws[wn + tj * 16 + lm][ko * 8]);
#pragma unroll
        for (int ti = 0; ti < 2; ti++)
#pragma unroll
            for (int tj = 0; tj < 2; tj++)
                acc[ti][tj] = __builtin_amdgcn_mfma_f32_16x16x32_bf16(af[ti], bfr[tj], acc[ti][tj], 0, 0, 0);
        __syncthreads();
    }

    if constexpr (EPI == 4) {
        __shared__ float Cs[64][65];
#pragma unroll
        for (int ti = 0; ti < 2; ti++)
#pragma unroll
            for (int tj = 0; tj < 2; tj++) {
                int nn = n0 + wn + tj * 16 + lm;
#pragma unroll
                for (int reg = 0; reg < 4; reg++) {
                    int m = m0 + wm + ti * 16 + ko * 4 + reg;
                    float v = acc[ti][tj][reg];
                    if (nn < N) v += aux[(size_t)m * DM + nn];
                    Cs[wm + ti * 16 + ko * 4 + reg][wn + tj * 16 + lm] = v;
                }
            }
        __syncthreads();
        float g = scal[0];
#pragma unroll
        for (int rep = 0; rep < 16; rep++) {
            int idx = rep * 256 + tid;
            int n = idx >> 6, mi = idx & 63;
            int nn = n0 + n;
            if (nn >= N) continue;
            int m = m0 + mi;
            int b = m >> 12, hw = m & 4095;
            size_t oi = (((size_t)b * DM + nn) << 12) + hw;
            outp[oi] = xres[oi] + g * (Cs[mi][n] + bias[nn]);
        }
        return;
    }

#pragma unroll
    for (int ti = 0; ti < 2; ti++)
#pragma unroll
        for (int tj = 0; tj < 2; tj++) {
            int n = n0 + wn + tj * 16 + lm;
            if (n >= N) continue;
#pragma unroll
            for (int reg = 0; reg < 4; reg++) {
                int m = m0 + wm + ti * 16 + ko * 4 + reg;
                float v = acc[ti][tj][reg];
                if (EPI == 1) v += bias[n];
                if (EPI == 2) v = softplusf(v + bias[n]);
                if (EPI == 3) v *= scal[0];
                C[(size_t)m * ldc + n] = v;
            }
        }
}

// ---------------- depthwise conv4 + SiLU, float4 channel-vectorized ----------------
// thread = (row, colq) with colq = 4-channel group of xc's 384 cols; dir from colq.
// xz col of x-part = colq + dir*192. cwt: [4][384] transposed taps, cbcat: [384].
__global__ __launch_bounds__(256) void conv_silu_kernel(const float* __restrict__ xz,
                                                        const float* __restrict__ cwt,
                                                        const float* __restrict__ cbcat,
                                                        float* __restrict__ xc) {
    int idx = blockIdx.x * 256 + threadIdx.x;   // BL*96
    int colq = (idx % 96) << 2;
    int row = idx / 96;
    int dir = colq >= DM;
    int b = row >> 12, l = row & 4095;
    int xoff = colq + dir * DM;
    float4 acc = *reinterpret_cast<const float4*>(cbcat + colq);
#pragma unroll
    for (int k = 0; k < 4; k++) {
        int ls = dir ? (l + 3 - k) : (l - 3 + k);
        if (ls < 0 || ls >= SEQL) continue;
        float4 xv = *reinterpret_cast<const float4*>(xz + ((size_t)(b << 12) + ls) * 768 + xoff);
        float4 wv = *reinterpret_cast<const float4*>(cwt + k * 384 + colq);
        acc.x += wv.x * xv.x; acc.y += wv.y * xv.y;
        acc.z += wv.z * xv.z; acc.w += wv.w * xv.w;
    }
    float4 o;
    o.x = siluf(acc.x); o.y = siluf(acc.y); o.z = siluf(acc.z); o.w = siluf(acc.w);
    *reinterpret_cast<float4*>(xc + (size_t)row * 384 + colq) = o;
}

// ---------------- chunked scan, pass A: thread=(b,dir,chunk,d), h[16] in regs ----------------
__global__ __launch_bounds__(192) void scan_partial(const float* __restrict__ dtb,
                                                    const float* __restrict__ xcb,
                                                    const float* __restrict__ xd0,
                                                    const float* __restrict__ xd1,
                                                    const float* __restrict__ Alog0,
                                                    const float* __restrict__ Alog1,
                                                    float* __restrict__ S, float* __restrict__ P) {
    int d = threadIdx.x;
    int blk = blockIdx.x;              // dirb*NCH + chunk
    int chunk = blk & (NCH - 1);
    int dirb = blk >> 7;
    int b = dirb >> 1, dir = dirb & 1;
    const float* xd   = dir ? xd1 : xd0;
    const float* Alog = dir ? Alog1 : Alog0;
    float A[16], h[16];
#pragma unroll
    for (int n = 0; n < 16; n++) { A[n] = -__expf(Alog[d * NST + n]); h[n] = 0.f; }
    float sdt = 0.f;
    int col = dir * DM + d;
    int l0 = chunk * CT;
    for (int s = 0; s < CT; s++) {
        int l = dir ? (SEQL - 1 - (l0 + s)) : (l0 + s);
        size_t row = ((size_t)b << 12) + l;
        float dtv = dtb[row * 384 + col];
        float xcv = xcb[row * 384 + col];
        const float4* Bp = reinterpret_cast<const float4*>(xd + row * XDP + DTR);
        float4 Bq[4] = { Bp[0], Bp[1], Bp[2], Bp[3] };
        const float* Bf = reinterpret_cast<const float*>(Bq);
        float dx = dtv * xcv;
#pragma unroll
        for (int n = 0; n < 16; n++)
            h[n] = __expf(dtv * A[n]) * h[n] + dx * Bf[n];
        sdt += dtv;
    }
    float4* Sp = reinterpret_cast<float4*>(S + (size_t)blk * 3072 + d * 16);
    float4* Pp = reinterpret_cast<float4*>(P + (size_t)blk * 3072 + d * 16);
#pragma unroll
    for (int q = 0; q < 4; q++) {
        Sp[q] = make_float4(h[q * 4], h[q * 4 + 1], h[q * 4 + 2], h[q * 4 + 3]);
        Pp[q] = make_float4(__expf(A[q * 4] * sdt), __expf(A[q * 4 + 1] * sdt),
                            __expf(A[q * 4 + 2] * sdt), __expf(A[q * 4 + 3] * sdt));
    }
}

// ---------------- pass B: sequential combine over chunks, in place (S -> Hini) ----------------
__global__ __launch_bounds__(256) void scan_combine(float* SH, const float* __restrict__ P) {
    int id = blockIdx.x * 256 + threadIdx.x;    // 4*3072
    int dirb = id / 3072;
    int dn = id % 3072;
    float h = 0.f;
#pragma unroll 4
    for (int c = 0; c < NCH; c++) {
        size_t idx = (size_t)(dirb * NCH + c) * 3072 + dn;
        float s = SH[idx], p = P[idx];
        SH[idx] = h;
        h = p * h + s;
    }
}

// ---------------- pass C: replay with true init, fused y = (h.C + D*x)*silu(z) ----------------
__global__ __launch_bounds__(192) void scan_apply(const float* __restrict__ dtb,
                                                  const float* __restrict__ xcb,
                                                  const float* __restrict__ xd0,
                                                  const float* __restrict__ xd1,
                                                  const float* __restrict__ xzb,
                                                  const float* __restrict__ Alog0,
                                                  const float* __restrict__ Alog1,
                                                  const float* __restrict__ D0,
                                                  const float* __restrict__ D1,
                                                  const float* __restrict__ Hini,
                                                  float* __restrict__ y) {
    int d = threadIdx.x;
    int blk = blockIdx.x;
    int chunk = blk & (NCH - 1);
    int dirb = blk >> 7;
    int b = dirb >> 1, dir = dirb & 1;
    const float* xd   = dir ? xd1 : xd0;
    const float* Alog = dir ? Alog1 : Alog0;
    float Dv = (dir ? D1 : D0)[d];
    float A[16], h[16];
#pragma unroll
    for (int n = 0; n < 16; n++) A[n] = -__expf(Alog[d * NST + n]);
    const float4* Hp = reinterpret_cast<const float4*>(Hini + (size_t)blk * 3072 + d * 16);
#pragma unroll
    for (int q = 0; q < 4; q++) {
        float4 hq = Hp[q];
        h[q * 4] = hq.x; h[q * 4 + 1] = hq.y; h[q * 4 + 2] = hq.z; h[q * 4 + 3] = hq.w;
    }
    int col = dir * DM + d;
    int l0 = chunk * CT;
    for (int s = 0; s < CT; s++) {
        int l = dir ? (SEQL - 1 - (l0 + s)) : (l0 + s);
        size_t row = ((size_t)b << 12) + l;
        float dtv = dtb[row * 384 + col];
        float xcv = xcb[row * 384 + col];
        const float4* Bp = reinterpret_cast<const float4*>(xd + row * XDP + DTR);
        const float4* Cp = reinterpret_cast<const float4*>(xd + row * XDP + DTR + NST);
        float4 Bq[4] = { Bp[0], Bp[1], Bp[2], Bp[3] };
        float4 Cq[4] = { Cp[0], Cp[1], Cp[2], Cp[3] };
        const float* Bf = reinterpret_cast<const float*>(Bq);
        const float* Cf = reinterpret_cast<const float*>(Cq);
        float dx = dtv * xcv;
        float p = 0.f;
#pragma unroll
        for (int n = 0; n < 16; n++) {
            h[n] = __expf(dtv * A[n]) * h[n] + dx * Bf[n];
            p += h[n] * Cf[n];
        }
        float zv = xzb[row * 768 + dir * 384 + DM + d];
        y[row * 384 + col] = (p + Dv * xcv) * siluf(zv);
    }
}

// ---------------- pack weights: in-proj concat, out-proj concat, dw/conv transposes ----------------
#define PK_IN   (768 * 192)
#define PK_OUT  (192 * 384)
#define PK_DWT  (9 * 768)
#define PK_CWT  (4 * 384)
#define PK_CB   384
#define PK_TOT  (PK_IN + PK_OUT + PK_DWT + PK_CWT + PK_CB)
__global__ void pack_weights(const float* __restrict__ iw0, const float* __restrict__ iw1,
                             const float* __restrict__ ow0, const float* __restrict__ ow1,
                             const float* __restrict__ dww,
                             const float* __restrict__ cw0, const float* __restrict__ cw1,
                             const float* __restrict__ cb0, const float* __restrict__ cb1,
                             float* __restrict__ win, float* __restrict__ wcat,
                             float* __restrict__ dwt, float* __restrict__ cwt,
                             float* __restrict__ cbc) {
    int idx = blockIdx.x * 256 + threadIdx.x;
    if (idx < PK_IN) {
        win[idx] = (idx < 384 * 192) ? iw0[idx] : iw1[idx - 384 * 192];
    } else if (idx < PK_IN + PK_OUT) {
        int j = idx - PK_IN;
        int n = j / 384, k = j % 384;
        wcat[j] = (k < DM) ? ow0[n * DM + k] : ow1[n * DM + k - DM];
    } else if (idx < PK_IN + PK_OUT + PK_DWT) {
        int j = idx - PK_IN - PK_OUT;
        int wi = j / 768, c = j % 768;
        dwt[j] = dww[c * 9 + wi];
    } else if (idx < PK_IN + PK_OUT + PK_DWT + PK_CWT) {
        int j = idx - PK_IN - PK_OUT - PK_DWT;
        int k = j / 384, col = j % 384;
        int dir = col >= DM, d = col - dir * DM;
        cwt[j] = (dir ? cw1 : cw0)[d * 4 + k];
    } else if (idx < PK_TOT) {
        int col = idx - PK_IN - PK_OUT - PK_DWT - PK_CWT;
        int dir = col >= DM, d = col - dir * DM;
        cbc[col] = (dir ? cb1 : cb0)[d];
    }
}

// ---------------- depthwise 3x3 + SimpleGate, float4 channel-vectorized ----------------
// dwt: [9][768] transposed weights (L1-hot), dwb original [768].
__global__ __launch_bounds__(256) void dwgate_kernel(const float* __restrict__ t,
                                                     const float* __restrict__ dwt,
                                                     const float* __restrict__ dwb,
                                                     float* __restrict__ g) {
    int idx = blockIdx.x * 256 + threadIdx.x;   // BL*96
    int jq = (idx % 96) << 2;
    int row = idx / 96;
    int b = row >> 12, hw = row & 4095;
    int h = hw >> 6, w = hw & 63;
    float4 a1 = *reinterpret_cast<const float4*>(dwb + jq);
    float4 a2 = *reinterpret_cast<const float4*>(dwb + 384 + jq);
#pragma unroll
    for (int dy = -1; dy <= 1; dy++) {
        int hh = h + dy;
        if (hh < 0 || hh >= 64) continue;
#pragma unroll
        for (int dx = -1; dx <= 1; dx++) {
            int ww = w + dx;
            if (ww < 0 || ww >= 64) continue;
            size_t base = ((size_t)(b << 12) + (hh << 6) + ww) * 768;
            int wi = (dy + 1) * 3 + (dx + 1);
            float4 t1 = *reinterpret_cast<const float4*>(t + base + jq);
            float4 t2 = *reinterpret_cast<const float4*>(t + base + 384 + jq);
            float4 w1 = *reinterpret_cast<const float4*>(dwt + wi * 768 + jq);
            float4 w2 = *reinterpret_cast<const float4*>(dwt + wi * 768 + 384 + jq);
            a1.x += w1.x * t1.x; a1.y += w1.y * t1.y; a1.z += w1.z * t1.z; a1.w += w1.w * t1.w;
            a2.x += w2.x * t2.x; a2.y += w2.y * t2.y; a2.z += w2.z * t2.z; a2.w += w2.w * t2.w;
        }
    }
    float4 o;
    o.x = a1.x * sigf(a2.x); o.y = a1.y * sigf(a2.y);
    o.z = a1.z * sigf(a2.z); o.w = a1.w * sigf(a2.w);
    *reinterpret_cast<float4*>(g + (size_t)row * 384 + jq) = o;
}

extern "C" void kernel_launch(void* const* d_in, const int* in_sizes, int n_in,
                              void* d_out, int out_size, void* d_ws, size_t ws_size,
                              hipStream_t stream) {
    const float* x         = (const float*)d_in[0];
    const float* ln_w      = (const float*)d_in[1];
    const float* ln_b      = (const float*)d_in[2];
    const float* scale_mod = (const float*)d_in[3];
    const float* c1w       = (const float*)d_in[4];
    const float* c1b       = (const float*)d_in[5];
    const float* dww       = (const float*)d_in[6];
    const float* dwb       = (const float*)d_in[7];
    const float* c2w       = (const float*)d_in[8];
    const float* c2b       = (const float*)d_in[9];
    const float* gamma     = (const float*)d_in[10];
    const float* in_w0     = (const float*)d_in[11];
    const float* conv_w0   = (const float*)d_in[12];
    const float* conv_b0   = (const float*)d_in[13];
    const float* xproj_w0  = (const float*)d_in[14];
    const float* dt_w0     = (const float*)d_in[15];
    const float* dt_b0     = (const float*)d_in[16];
    const float* A_log0    = (const float*)d_in[17];
    const float* D0        = (const float*)d_in[18];
    const float* out_w0    = (const float*)d_in[19];
    const float* in_w1     = (const float*)d_in[20];
    const float* conv_w1   = (const float*)d_in[21];
    const float* conv_b1   = (const float*)d_in[22];
    const float* xproj_w1  = (const float*)d_in[23];
    const float* dt_w1     = (const float*)d_in[24];
    const float* dt_b1     = (const float*)d_in[25];
    const float* A_log1    = (const float*)d_in[26];
    const float* D1        = (const float*)d_in[27];
    const float* out_w1    = (const float*)d_in[28];

    float* wsf = (float*)d_ws;
    // workspace layout (floats), total ~19.9 MB*4 (~79.6 MB)
    const size_t o_xn  = 0;                         // BL*192; dead after in-proj -> reused as S/Hini
    const size_t o_xz  = o_xn  + (size_t)BLR * DM;  // BL*768 (reused as SGFN t)
    const size_t o_xc  = o_xz  + (size_t)BLR * 768; // BL*384 (reused as SGFN g)
    const size_t o_dt  = o_xc  + (size_t)BLR * 384; // BL*384
    const size_t o_y   = o_dt  + (size_t)BLR * 384; // BL*384
    const size_t o_xm  = o_y   + (size_t)BLR * 384; // BL*192; free until out-proj -> reused as P
    const size_t o_xd0 = o_xm  + (size_t)BLR * DM;  // BL*48 (padded)
    const size_t o_xd1 = o_xd0 + (size_t)BLR * XDP; // BL*48
    const size_t o_wc  = o_xd1 + (size_t)BLR * XDP; // 192*384
    const size_t o_wi  = o_wc  + (size_t)DM * 384;  // 768*192
    const size_t o_dwt = o_wi  + (size_t)PK_IN;     // 9*768
    const size_t o_cwt = o_dwt + PK_DWT;            // 4*384
    const size_t o_cb  = o_cwt + PK_CWT;            // 384

    float* S_H = wsf + o_xn;   // 4*NCH*3072 = 1.57M floats == BL*192 exactly
    float* Pb  = wsf + o_xm;   // same size

    // 1. LayerNorm
    ln_kernel<<<BLR / 4, 256, 0, stream>>>(x, ln_w, ln_b, wsf + o_xn);
    // 2. pack/transpose weights
    pack_weights<<<(PK_TOT + 255) / 256, 256, 0, stream>>>(in_w0, in_w1, out_w0, out_w1,
                                                           dww, conv_w0, conv_w1, conv_b0, conv_b1,
                                                           wsf + o_wi, wsf + o_wc,
                                                           wsf + o_dwt, wsf + o_cwt, wsf + o_cb);
    // 3. merged in-proj GEMM (both dirs) -> xz [BL, 768]
    gemm_mfma<0><<<dim3(12, 128), 256, 0, stream>>>(wsf + o_xn, DM, wsf + o_wi, DM, wsf + o_xz, 768,
                                                    768, DM, nullptr, nullptr, nullptr, nullptr, nullptr);
    // 4. depthwise conv4 + SiLU -> xc [BL,384]
    conv_silu_kernel<<<(BLR * 96) / 256, 256, 0, stream>>>(wsf + o_xz, wsf + o_cwt, wsf + o_cb,
                                                           wsf + o_xc);
    // 5-6. x-proj GEMMs -> xd [BL,48pad] per dir
    gemm_mfma<0><<<dim3(1, 128), 256, 0, stream>>>(wsf + o_xc, 384, xproj_w0, DM, wsf + o_xd0, XDP,
                                                   XDW, DM, nullptr, nullptr, nullptr, nullptr, nullptr);
    gemm_mfma<0><<<dim3(1, 128), 256, 0, stream>>>(wsf + o_xc + DM, 384, xproj_w1, DM, wsf + o_xd1, XDP,
                                                   XDW, DM, nullptr, nullptr, nullptr, nullptr, nullptr);
    // 7-8. dt-proj + softplus -> dt [BL,384]
    gemm_mfma<2><<<dim3(3, 128), 256, 0, stream>>>(wsf + o_xd0, XDP, dt_w0, DTR, wsf + o_dt, 384,
                                                   DM, DTR, dt_b0, nullptr, nullptr, nullptr, nullptr);
    gemm_mfma<2><<<dim3(3, 128), 256, 0, stream>>>(wsf + o_xd1, XDP, dt_w1, DTR, wsf + o_dt + DM, 384,
                                                   DM, DTR, dt_b1, nullptr, nullptr, nullptr, nullptr);
    // 9-11. chunked selective scan -> y [BL,384]
    scan_partial<<<4 * NCH, 192, 0, stream>>>(wsf + o_dt, wsf + o_xc, wsf + o_xd0, wsf + o_xd1,
                                              A_log0, A_log1, S_H, Pb);
    scan_combine<<<48, 256, 0, stream>>>(S_H, Pb);
    scan_apply<<<4 * NCH, 192, 0, stream>>>(wsf + o_dt, wsf + o_xc, wsf + o_xd0, wsf + o_xd1,
                                            wsf + o_xz, A_log0, A_log1, D0, D1, S_H, wsf + o_y);
    // 12. out-proj (packed K=384) with scale_mod -> xm [BL,192]
    gemm_mfma<3><<<dim3(3, 128), 256, 0, stream>>>(wsf + o_y, 384, wsf + o_wc, 384, wsf + o_xm, DM,
                                                   DM, 384, nullptr, scale_mod, nullptr, nullptr, nullptr);
    // 13. SGFN conv1x1 #1 -> t (reuses xz region)
    gemm_mfma<1><<<dim3(12, 128), 256, 0, stream>>>(wsf + o_xm, DM, c1w, DM, wsf + o_xz, 768,
                                                    768, DM, c1b, nullptr, nullptr, nullptr, nullptr);
    // 14. depthwise 3x3 + gate -> g (reuses xc region)
    dwgate_kernel<<<(BLR * 96) / 256, 256, 0, stream>>>(wsf + o_xz, wsf + o_dwt, dwb, wsf + o_xc);
    // 15. SGFN conv1x1 #2 + final residual -> d_out (fp32, NCHW)
    gemm_mfma<4><<<dim3(3, 128), 256, 0, stream>>>(wsf + o_xc, 384, c2w, 384, wsf + o_y, DM,
                                                   DM, 384, c2b, gamma, wsf + o_xm, x, (float*)d_out);
}

// Round 6
// 289.659 us; speedup vs baseline: 2.1910x; 1.1013x over previous
//
#include <hip/hip_runtime.h>
#include <hip/hip_bf16.h>

#define BSZ   2
#define SEQL  4096
#define BLR   8192      // BSZ * SEQL rows
#define DM    192
#define NST   16
#define DTR   12
#define XDW   44        // DTR + 2*NST
#define XDP   48        // padded leading dim for xd rows (96 B, 16B-aligned)
#define NCH   128       // scan chunks
#define CT    32        // chunk length (NCH*CT == SEQL)

typedef float f32x4 __attribute__((ext_vector_type(4)));
typedef __bf16 bf16x8 __attribute__((ext_vector_type(8)));
typedef __bf16 bf16x4 __attribute__((ext_vector_type(4)));

__device__ __forceinline__ float sigf(float x) { return 1.f / (1.f + __expf(-x)); }
__device__ __forceinline__ float siluf(float x) { return x * sigf(x); }
__device__ __forceinline__ float softplusf(float x) { return x > 20.f ? x : log1pf(__expf(x)); }

// ---------------- LayerNorm: NCHW fp32 -> [BL,192] bf16, LDS-transposed coalesced ----------------
// one block per 64 consecutive hw positions of one batch image
__global__ __launch_bounds__(256) void ln_kernel(const float* __restrict__ x,
                                                 const float* __restrict__ lw,
                                                 const float* __restrict__ lb,
                                                 __bf16* __restrict__ xn) {
    __shared__ float Xs[192][68];   // pad 68: float4-aligned rows
    __shared__ float Rs[4][64], Rq[4][64];
    __shared__ float Mu[64], Rv[64];
    const int tid = threadIdx.x;
    const int blk = blockIdx.x;          // 128 blocks
    const int b = blk >> 6;
    const int hw0 = (blk & 63) << 6;
    // coalesced load: 16 channels per sweep, float4 over hw
    {
        int i4 = tid & 15, cp = tid >> 4;
        for (int c = cp; c < 192; c += 16) {
            float4 v = *reinterpret_cast<const float4*>(x + ((size_t)b * DM + c) * 4096 + hw0 + i4 * 4);
            *reinterpret_cast<float4*>(&Xs[c][i4 * 4]) = v;
        }
    }
    __syncthreads();
    const int i = tid & 63, part = tid >> 6;
    float s = 0.f, q = 0.f;
    for (int c = part * 48; c < part * 48 + 48; c++) {
        float v = Xs[c][i];
        s += v; q += v * v;
    }
    Rs[part][i] = s; Rq[part][i] = q;
    __syncthreads();
    if (part == 0) {
        float ss = Rs[0][i] + Rs[1][i] + Rs[2][i] + Rs[3][i];
        float qq = Rq[0][i] + Rq[1][i] + Rq[2][i] + Rq[3][i];
        float mu = ss * (1.f / DM);
        float var = qq * (1.f / DM) - mu * mu;
        Mu[i] = mu; Rv[i] = rsqrtf(var + 1e-5f);
    }
    __syncthreads();
    float mu = Mu[i], rs = Rv[i];
    size_t rowb = ((size_t)b * 4096 + hw0 + i) * DM;
#pragma unroll
    for (int j = 0; j < 6; j++) {
        int c0 = part * 48 + j * 8;
        bf16x8 o;
#pragma unroll
        for (int e = 0; e < 8; e++) {
            int c = c0 + e;
            o[e] = (__bf16)((Xs[c][i] - mu) * rs * lw[c] + lb[c]);
        }
        *reinterpret_cast<bf16x8*>(xn + rowb + c0) = o;
    }
}

// ---------------- MFMA bf16 NT GEMM: C[m,n] = sum_k A[m,k] * W[n,k] (all bf16, fp32 acc) ----------
// EPI: 0 plain, 1 +bias, 3 *scalar, 4 final residual (fp32 NCHW out), 5 dual-dir xproj (EPI0 body)
template <int EPI>
__global__ __launch_bounds__(256) void gemm_mfma(const __bf16* __restrict__ A, int lda,
                                                 const __bf16* __restrict__ W, int ldw,
                                                 __bf16* __restrict__ C, int ldc,
                                                 int N, int K,
                                                 const float* __restrict__ bias,
                                                 const float* __restrict__ scal,
                                                 const __bf16* __restrict__ aux,
                                                 const float* __restrict__ xres,
                                                 float* __restrict__ outp) {
    __shared__ __bf16 As[64][40];
    __shared__ __bf16 Ws[64][40];
    const int tid  = threadIdx.x;
    const int wave = tid >> 6, lane = tid & 63;
    const int ko = lane >> 4, lm = lane & 15;
    const int wm = (wave & 1) * 32, wn = (wave >> 1) * 32;
    const int m0 = blockIdx.y << 6;
    int n0 = blockIdx.x << 6;
    if (EPI == 5) {                 // dual-dir xproj: blockIdx.x = dir
        int dir = blockIdx.x;
        A += dir * DM;              // xc column half
        W += (size_t)dir * XDW * DM;
        C += (size_t)dir * BLR * XDP;
        n0 = 0;
    }
    const int r = tid >> 2, cq = (tid & 3) * 8;   // staging: 64 rows x 32 cols, 8 bf16/thread
    f32x4 acc[2][2] = {};

    for (int k0 = 0; k0 < K; k0 += 32) {
        {   // A tile
            bf16x8 pk;
            const __bf16* ap = A + (size_t)(m0 + r) * lda + k0 + cq;
            if (k0 + cq + 8 <= K) pk = *reinterpret_cast<const bf16x8*>(ap);
            else {
#pragma unroll
                for (int j = 0; j < 8; j++) pk[j] = (k0 + cq + j < K) ? ap[j] : (__bf16)0.f;
            }
            *reinterpret_cast<bf16x8*>(&As[r][cq]) = pk;
        }
        {   // W tile
            bf16x8 pk = {};
            if (n0 + r < N) {
                const __bf16* wp = W + (size_t)(n0 + r) * ldw + k0 + cq;
                if (k0 + cq + 8 <= K) pk = *reinterpret_cast<const bf16x8*>(wp);
                else {
#pragma unroll
                    for (int j = 0; j < 8; j++) pk[j] = (k0 + cq + j < K) ? wp[j] : (__bf16)0.f;
                }
            }
            *reinterpret_cast<bf16x8*>(&Ws[r][cq]) = pk;
        }
        __syncthreads();
        bf16x8 af[2], bfr[2];
#pragma unroll
        for (int ti = 0; ti < 2; ti++)
            af[ti] = *reinterpret_cast<bf16x8*>(&As[wm + ti * 16 + lm][ko * 8]);
#pragma unroll
        for (int tj = 0; tj < 2; tj++)
            bfr[tj] = *reinterpret_cast<bf16x8*>(&Ws[wn + tj * 16 + lm][ko * 8]);
#pragma unroll
        for (int ti = 0; ti < 2; ti++)
#pragma unroll
            for (int tj = 0; tj < 2; tj++)
                acc[ti][tj] = __builtin_amdgcn_mfma_f32_16x16x32_bf16(af[ti], bfr[tj], acc[ti][tj], 0, 0, 0);
        __syncthreads();
    }

    if constexpr (EPI == 4) {
        __shared__ float Cs[64][65];
#pragma unroll
        for (int ti = 0; ti < 2; ti++)
#pragma unroll
            for (int tj = 0; tj < 2; tj++) {
                int nn = n0 + wn + tj * 16 + lm;
#pragma unroll
                for (int reg = 0; reg < 4; reg++) {
                    int m = m0 + wm + ti * 16 + ko * 4 + reg;
                    float v = acc[ti][tj][reg];
                    if (nn < N) v += (float)aux[(size_t)m * DM + nn];
                    Cs[wm + ti * 16 + ko * 4 + reg][wn + tj * 16 + lm] = v;
                }
            }
        __syncthreads();
        float g = scal[0];
#pragma unroll
        for (int rep = 0; rep < 16; rep++) {
            int idx = rep * 256 + tid;
            int n = idx >> 6, mi = idx & 63;
            int nn = n0 + n;
            if (nn >= N) continue;
            int m = m0 + mi;
            int b = m >> 12, hw = m & 4095;
            size_t oi = (((size_t)b * DM + nn) << 12) + hw;
            outp[oi] = xres[oi] + g * (Cs[mi][n] + bias[nn]);
        }
        return;
    }

#pragma unroll
    for (int ti = 0; ti < 2; ti++)
#pragma unroll
        for (int tj = 0; tj < 2; tj++) {
            int n = n0 + wn + tj * 16 + lm;
            if (n >= N) continue;
#pragma unroll
            for (int reg = 0; reg < 4; reg++) {
                int m = m0 + wm + ti * 16 + ko * 4 + reg;
                float v = acc[ti][tj][reg];
                if (EPI == 1) v += bias[n];
                if (EPI == 3) v *= scal[0];
                C[(size_t)m * ldc + n] = (__bf16)v;
            }
        }
}

// ---------------- depthwise conv4 + SiLU, bf16x8 channel-vectorized ----------------
__global__ __launch_bounds__(256) void conv_silu_kernel(const __bf16* __restrict__ xz,
                                                        const float* __restrict__ cwt,
                                                        const float* __restrict__ cbcat,
                                                        __bf16* __restrict__ xc) {
    int idx = blockIdx.x * 256 + threadIdx.x;   // BL*48
    int colq = (idx % 48) << 3;
    int row = idx / 48;
    int dir = colq >= DM;
    int b = row >> 12, l = row & 4095;
    int xoff = colq + dir * DM;
    float acc[8];
    {
        float4 b0 = *reinterpret_cast<const float4*>(cbcat + colq);
        float4 b1 = *reinterpret_cast<const float4*>(cbcat + colq + 4);
        acc[0] = b0.x; acc[1] = b0.y; acc[2] = b0.z; acc[3] = b0.w;
        acc[4] = b1.x; acc[5] = b1.y; acc[6] = b1.z; acc[7] = b1.w;
    }
#pragma unroll
    for (int k = 0; k < 4; k++) {
        int ls = dir ? (l + 3 - k) : (l - 3 + k);
        if (ls < 0 || ls >= SEQL) continue;
        bf16x8 xv = *reinterpret_cast<const bf16x8*>(xz + ((size_t)(b << 12) + ls) * 768 + xoff);
        const float* wv = cwt + k * 384 + colq;
#pragma unroll
        for (int e = 0; e < 8; e++) acc[e] += wv[e] * (float)xv[e];
    }
    bf16x8 o;
#pragma unroll
    for (int e = 0; e < 8; e++) o[e] = (__bf16)siluf(acc[e]);
    *reinterpret_cast<bf16x8*>(xc + (size_t)row * 384 + colq) = o;
}

// ---------------- scan pass A: thread=(b,dir,chunk,d); dt fused; h[16] in regs -----------------
// xd row layout (bf16, ld=48): [B(16) | C(16) | dtr(12) | pad(4)]
__global__ __launch_bounds__(192) void scan_partial(const __bf16* __restrict__ xcb,
                                                    const __bf16* __restrict__ xd,
                                                    const float* __restrict__ dtw0,
                                                    const float* __restrict__ dtw1,
                                                    const float* __restrict__ dtb0,
                                                    const float* __restrict__ dtb1,
                                                    const float* __restrict__ Alog0,
                                                    const float* __restrict__ Alog1,
                                                    float* __restrict__ S, float* __restrict__ P) {
    int d = threadIdx.x;
    int blk = blockIdx.x;              // dirb*NCH + chunk
    int chunk = blk & (NCH - 1);
    int dirb = blk >> 7;
    int b = dirb >> 1, dir = dirb & 1;
    const float* Alog = dir ? Alog1 : Alog0;
    const float* dtw  = dir ? dtw1 : dtw0;
    float dtb = (dir ? dtb1 : dtb0)[d];
    float wdt[12];
#pragma unroll
    for (int r = 0; r < 12; r++) wdt[r] = dtw[d * DTR + r];
    float A[16], h[16];
#pragma unroll
    for (int n = 0; n < 16; n++) { A[n] = -__expf(Alog[d * NST + n]); h[n] = 0.f; }
    float sdt = 0.f;
    int col = dir * DM + d;
    const __bf16* xdd = xd + (size_t)dir * BLR * XDP;
    int l0 = chunk * CT;
    for (int s = 0; s < CT; s++) {
        int l = dir ? (SEQL - 1 - (l0 + s)) : (l0 + s);
        size_t row = ((size_t)b << 12) + l;
        const __bf16* xr = xdd + row * XDP;
        bf16x8 B0 = *reinterpret_cast<const bf16x8*>(xr);
        bf16x8 B1 = *reinterpret_cast<const bf16x8*>(xr + 8);
        bf16x8 R0 = *reinterpret_cast<const bf16x8*>(xr + 32);
        bf16x4 R1 = *reinterpret_cast<const bf16x4*>(xr + 40);
        float dtraw = dtb;
#pragma unroll
        for (int r = 0; r < 8; r++) dtraw += wdt[r] * (float)R0[r];
#pragma unroll
        for (int r = 0; r < 4; r++) dtraw += wdt[8 + r] * (float)R1[r];
        float dtv = softplusf(dtraw);
        float xcv = (float)xcb[row * 384 + col];
        float dx = dtv * xcv;
#pragma unroll
        for (int n = 0; n < 16; n++) {
            float Bv = (float)(n < 8 ? B0[n & 7] : B1[n & 7]);
            h[n] = __expf(dtv * A[n]) * h[n] + dx * Bv;
        }
        sdt += dtv;
    }
    float4* Sp = reinterpret_cast<float4*>(S + (size_t)blk * 3072 + d * 16);
    float4* Pp = reinterpret_cast<float4*>(P + (size_t)blk * 3072 + d * 16);
#pragma unroll
    for (int q = 0; q < 4; q++) {
        Sp[q] = make_float4(h[q * 4], h[q * 4 + 1], h[q * 4 + 2], h[q * 4 + 3]);
        Pp[q] = make_float4(__expf(A[q * 4] * sdt), __expf(A[q * 4 + 1] * sdt),
                            __expf(A[q * 4 + 2] * sdt), __expf(A[q * 4 + 3] * sdt));
    }
}

// ---------------- pass B: sequential combine over chunks, in place (S -> Hini) ----------------
__global__ __launch_bounds__(256) void scan_combine(float* SH, const float* __restrict__ P) {
    int id = blockIdx.x * 256 + threadIdx.x;    // 4*3072
    int dirb = id / 3072;
    int dn = id % 3072;
    float h = 0.f;
#pragma unroll 4
    for (int c = 0; c < NCH; c++) {
        size_t idx = (size_t)(dirb * NCH + c) * 3072 + dn;
        float s = SH[idx], p = P[idx];
        SH[idx] = h;
        h = p * h + s;
    }
}

// ---------------- pass C: replay with true init, fused y = (h.C + D*x)*silu(z) ----------------
__global__ __launch_bounds__(192) void scan_apply(const __bf16* __restrict__ xcb,
                                                  const __bf16* __restrict__ xd,
                                                  const __bf16* __restrict__ xzb,
                                                  const float* __restrict__ dtw0,
                                                  const float* __restrict__ dtw1,
                                                  const float* __restrict__ dtb0,
                                                  const float* __restrict__ dtb1,
                                                  const float* __restrict__ Alog0,
                                                  const float* __restrict__ Alog1,
                                                  const float* __restrict__ D0,
                                                  const float* __restrict__ D1,
                                                  const float* __restrict__ Hini,
                                                  __bf16* __restrict__ y) {
    int d = threadIdx.x;
    int blk = blockIdx.x;
    int chunk = blk & (NCH - 1);
    int dirb = blk >> 7;
    int b = dirb >> 1, dir = dirb & 1;
    const float* Alog = dir ? Alog1 : Alog0;
    const float* dtw  = dir ? dtw1 : dtw0;
    float dtb = (dir ? dtb1 : dtb0)[d];
    float Dv = (dir ? D1 : D0)[d];
    float wdt[12];
#pragma unroll
    for (int r = 0; r < 12; r++) wdt[r] = dtw[d * DTR + r];
    float A[16], h[16];
#pragma unroll
    for (int n = 0; n < 16; n++) A[n] = -__expf(Alog[d * NST + n]);
    const float4* Hp = reinterpret_cast<const float4*>(Hini + (size_t)blk * 3072 + d * 16);
#pragma unroll
    for (int q = 0; q < 4; q++) {
        float4 hq = Hp[q];
        h[q * 4] = hq.x; h[q * 4 + 1] = hq.y; h[q * 4 + 2] = hq.z; h[q * 4 + 3] = hq.w;
    }
    int col = dir * DM + d;
    const __bf16* xdd = xd + (size_t)dir * BLR * XDP;
    int l0 = chunk * CT;
    for (int s = 0; s < CT; s++) {
        int l = dir ? (SEQL - 1 - (l0 + s)) : (l0 + s);
        size_t row = ((size_t)b << 12) + l;
        const __bf16* xr = xdd + row * XDP;
        bf16x8 B0 = *reinterpret_cast<const bf16x8*>(xr);
        bf16x8 B1 = *reinterpret_cast<const bf16x8*>(xr + 8);
        bf16x8 C0 = *reinterpret_cast<const bf16x8*>(xr + 16);
        bf16x8 C1 = *reinterpret_cast<const bf16x8*>(xr + 24);
        bf16x8 R0 = *reinterpret_cast<const bf16x8*>(xr + 32);
        bf16x4 R1 = *reinterpret_cast<const bf16x4*>(xr + 40);
        float dtraw = dtb;
#pragma unroll
        for (int r = 0; r < 8; r++) dtraw += wdt[r] * (float)R0[r];
#pragma unroll
        for (int r = 0; r < 4; r++) dtraw += wdt[8 + r] * (float)R1[r];
        float dtv = softplusf(dtraw);
        float xcv = (float)xcb[row * 384 + col];
        float dx = dtv * xcv;
        float p = 0.f;
#pragma unroll
        for (int n = 0; n < 16; n++) {
            float Bv = (float)(n < 8 ? B0[n & 7] : B1[n & 7]);
            float Cv = (float)(n < 8 ? C0[n & 7] : C1[n & 7]);
            h[n] = __expf(dtv * A[n]) * h[n] + dx * Bv;
            p += h[n] * Cv;
        }
        float zv = (float)xzb[row * 768 + dir * 384 + DM + d];
        y[row * 384 + col] = (__bf16)((p + Dv * xcv) * siluf(zv));
    }
}

// ---------------- pack/convert weights ----------------
#define PK_WIN  (768 * 192)
#define PK_WCT  (192 * 384)
#define PK_XPW  (2 * XDW * 192)
#define PK_C1W  (768 * 192)
#define PK_C2W  (192 * 384)
#define PK_DWT  (9 * 768)
#define PK_CWT  (4 * 384)
#define PK_CB   384
#define PK_TOT  (PK_WIN + PK_WCT + PK_XPW + PK_C1W + PK_C2W + PK_DWT + PK_CWT + PK_CB)
__global__ void pack_weights(const float* __restrict__ iw0, const float* __restrict__ iw1,
                             const float* __restrict__ ow0, const float* __restrict__ ow1,
                             const float* __restrict__ xp0, const float* __restrict__ xp1,
                             const float* __restrict__ c1w, const float* __restrict__ c2w,
                             const float* __restrict__ dww,
                             const float* __restrict__ cw0, const float* __restrict__ cw1,
                             const float* __restrict__ cb0, const float* __restrict__ cb1,
                             __bf16* __restrict__ win, __bf16* __restrict__ wcat,
                             __bf16* __restrict__ xpw, __bf16* __restrict__ c1wb,
                             __bf16* __restrict__ c2wb,
                             float* __restrict__ dwt, float* __restrict__ cwt,
                             float* __restrict__ cbc) {
    int idx = blockIdx.x * 256 + threadIdx.x;
    int base = 0;
    if (idx < base + PK_WIN) {
        int j = idx - base;
        win[j] = (__bf16)((j < 384 * 192) ? iw0[j] : iw1[j - 384 * 192]);
        return;
    }
    base += PK_WIN;
    if (idx < base + PK_WCT) {
        int j = idx - base;
        int n = j / 384, k = j % 384;
        wcat[j] = (__bf16)((k < DM) ? ow0[n * DM + k] : ow1[n * DM + k - DM]);
        return;
    }
    base += PK_WCT;
    if (idx < base + PK_XPW) {
        int j = idx - base;
        int dir = j / (XDW * 192);
        int rem = j - dir * (XDW * 192);
        int np = rem / 192, k = rem % 192;
        int src = (np < 32) ? (np + DTR) : (np - 32);   // [B|C|dtr] row order
        xpw[j] = (__bf16)((dir ? xp1 : xp0)[src * 192 + k]);
        return;
    }
    base += PK_XPW;
    if (idx < base + PK_C1W) {
        int j = idx - base;
        c1wb[j] = (__bf16)c1w[j];
        return;
    }
    base += PK_C1W;
    if (idx < base + PK_C2W) {
        int j = idx - base;
        c2wb[j] = (__bf16)c2w[j];
        return;
    }
    base += PK_C2W;
    if (idx < base + PK_DWT) {
        int j = idx - base;
        int wi = j / 768, c = j % 768;
        dwt[j] = dww[c * 9 + wi];
        return;
    }
    base += PK_DWT;
    if (idx < base + PK_CWT) {
        int j = idx - base;
        int k = j / 384, col = j % 384;
        int dir = col >= DM, d = col - dir * DM;
        cwt[j] = (dir ? cw1 : cw0)[d * 4 + k];
        return;
    }
    base += PK_CWT;
    if (idx < base + PK_CB) {
        int col = idx - base;
        int dir = col >= DM, d = col - dir * DM;
        cbc[col] = (dir ? cb1 : cb0)[d];
    }
}

// ---------------- depthwise 3x3 + SimpleGate, bf16x8 channel-vectorized ----------------
__global__ __launch_bounds__(256) void dwgate_kernel(const __bf16* __restrict__ t,
                                                     const float* __restrict__ dwt,
                                                     const float* __restrict__ dwb,
                                                     __bf16* __restrict__ g) {
    int idx = blockIdx.x * 256 + threadIdx.x;   // BL*48
    int jq = (idx % 48) << 3;
    int row = idx / 48;
    int b = row >> 12, hw = row & 4095;
    int h = hw >> 6, w = hw & 63;
    float a1[8], a2[8];
    {
        float4 x0 = *reinterpret_cast<const float4*>(dwb + jq);
        float4 x1 = *reinterpret_cast<const float4*>(dwb + jq + 4);
        float4 y0 = *reinterpret_cast<const float4*>(dwb + 384 + jq);
        float4 y1 = *reinterpret_cast<const float4*>(dwb + 384 + jq + 4);
        a1[0]=x0.x;a1[1]=x0.y;a1[2]=x0.z;a1[3]=x0.w;a1[4]=x1.x;a1[5]=x1.y;a1[6]=x1.z;a1[7]=x1.w;
        a2[0]=y0.x;a2[1]=y0.y;a2[2]=y0.z;a2[3]=y0.w;a2[4]=y1.x;a2[5]=y1.y;a2[6]=y1.z;a2[7]=y1.w;
    }
#pragma unroll
    for (int dy = -1; dy <= 1; dy++) {
        int hh = h + dy;
        if (hh < 0 || hh >= 64) continue;
#pragma unroll
        for (int dx = -1; dx <= 1; dx++) {
            int ww = w + dx;
            if (ww < 0 || ww >= 64) continue;
            size_t base = ((size_t)(b << 12) + (hh << 6) + ww) * 768;
            int wi = (dy + 1) * 3 + (dx + 1);
            bf16x8 t1 = *reinterpret_cast<const bf16x8*>(t + base + jq);
            bf16x8 t2 = *reinterpret_cast<const bf16x8*>(t + base + 384 + jq);
            const float* w1 = dwt + wi * 768 + jq;
            const float* w2 = dwt + wi * 768 + 384 + jq;
#pragma unroll
            for (int e = 0; e < 8; e++) {
                a1[e] += w1[e] * (float)t1[e];
                a2[e] += w2[e] * (float)t2[e];
            }
        }
    }
    bf16x8 o;
#pragma unroll
    for (int e = 0; e < 8; e++) o[e] = (__bf16)(a1[e] * sigf(a2[e]));
    *reinterpret_cast<bf16x8*>(g + (size_t)row * 384 + jq) = o;
}

extern "C" void kernel_launch(void* const* d_in, const int* in_sizes, int n_in,
                              void* d_out, int out_size, void* d_ws, size_t ws_size,
                              hipStream_t stream) {
    const float* x         = (const float*)d_in[0];
    const float* ln_w      = (const float*)d_in[1];
    const float* ln_b      = (const float*)d_in[2];
    const float* scale_mod = (const float*)d_in[3];
    const float* c1w       = (const float*)d_in[4];
    const float* c1b       = (const float*)d_in[5];
    const float* dww       = (const float*)d_in[6];
    const float* dwb       = (const float*)d_in[7];
    const float* c2w       = (const float*)d_in[8];
    const float* c2b       = (const float*)d_in[9];
    const float* gamma     = (const float*)d_in[10];
    const float* in_w0     = (const float*)d_in[11];
    const float* conv_w0   = (const float*)d_in[12];
    const float* conv_b0   = (const float*)d_in[13];
    const float* xproj_w0  = (const float*)d_in[14];
    const float* dt_w0     = (const float*)d_in[15];
    const float* dt_b0     = (const float*)d_in[16];
    const float* A_log0    = (const float*)d_in[17];
    const float* D0        = (const float*)d_in[18];
    const float* out_w0    = (const float*)d_in[19];
    const float* in_w1     = (const float*)d_in[20];
    const float* conv_w1   = (const float*)d_in[21];
    const float* conv_b1   = (const float*)d_in[22];
    const float* xproj_w1  = (const float*)d_in[23];
    const float* dt_w1     = (const float*)d_in[24];
    const float* dt_b1     = (const float*)d_in[25];
    const float* A_log1    = (const float*)d_in[26];
    const float* D1        = (const float*)d_in[27];
    const float* out_w1    = (const float*)d_in[28];

    char* wsb = (char*)d_ws;
    size_t off = 0;
    auto alloc = [&](size_t bytes) { size_t o = off; off += (bytes + 255) & ~(size_t)255; return o; };
    const size_t o_xn   = alloc((size_t)BLR * DM * 2);        // bf16
    const size_t o_xz   = alloc((size_t)BLR * 768 * 2);       // bf16 (reused as SGFN t)
    const size_t o_xc   = alloc((size_t)BLR * 384 * 2);       // bf16 (reused as SGFN g)
    const size_t o_y    = alloc((size_t)BLR * 384 * 2);       // bf16
    const size_t o_xm   = alloc((size_t)BLR * DM * 2);        // bf16
    const size_t o_xd   = alloc((size_t)2 * BLR * XDP * 2);   // bf16, both dirs
    const size_t o_S    = alloc((size_t)4 * NCH * 3072 * 4);  // fp32
    const size_t o_P    = alloc((size_t)4 * NCH * 3072 * 4);  // fp32
    const size_t o_win  = alloc((size_t)PK_WIN * 2);
    const size_t o_wct  = alloc((size_t)PK_WCT * 2);
    const size_t o_xpw  = alloc((size_t)PK_XPW * 2);
    const size_t o_c1w  = alloc((size_t)PK_C1W * 2);
    const size_t o_c2w  = alloc((size_t)PK_C2W * 2);
    const size_t o_dwt  = alloc((size_t)PK_DWT * 4);
    const size_t o_cwt  = alloc((size_t)PK_CWT * 4);
    const size_t o_cb   = alloc((size_t)PK_CB * 4);

    __bf16* xn  = (__bf16*)(wsb + o_xn);
    __bf16* xz  = (__bf16*)(wsb + o_xz);
    __bf16* xc  = (__bf16*)(wsb + o_xc);
    __bf16* yb  = (__bf16*)(wsb + o_y);
    __bf16* xm  = (__bf16*)(wsb + o_xm);
    __bf16* xd  = (__bf16*)(wsb + o_xd);
    float*  Sb  = (float*)(wsb + o_S);
    float*  Pb  = (float*)(wsb + o_P);
    __bf16* win = (__bf16*)(wsb + o_win);
    __bf16* wct = (__bf16*)(wsb + o_wct);
    __bf16* xpw = (__bf16*)(wsb + o_xpw);
    __bf16* c1wb= (__bf16*)(wsb + o_c1w);
    __bf16* c2wb= (__bf16*)(wsb + o_c2w);
    float*  dwt = (float*)(wsb + o_dwt);
    float*  cwt = (float*)(wsb + o_cwt);
    float*  cbc = (float*)(wsb + o_cb);

    // 1. LayerNorm (coalesced, LDS transpose) -> xn bf16
    ln_kernel<<<128, 256, 0, stream>>>(x, ln_w, ln_b, xn);
    // 2. pack/convert weights
    pack_weights<<<(PK_TOT + 255) / 256, 256, 0, stream>>>(in_w0, in_w1, out_w0, out_w1,
                                                           xproj_w0, xproj_w1, c1w, c2w,
                                                           dww, conv_w0, conv_w1, conv_b0, conv_b1,
                                                           win, wct, xpw, c1wb, c2wb, dwt, cwt, cbc);
    // 3. merged in-proj GEMM (both dirs) -> xz [BL,768] bf16
    gemm_mfma<0><<<dim3(12, 128), 256, 0, stream>>>(xn, DM, win, DM, xz, 768, 768, DM,
                                                    nullptr, nullptr, nullptr, nullptr, nullptr);
    // 4. depthwise conv4 + SiLU -> xc [BL,384] bf16
    conv_silu_kernel<<<(BLR * 48) / 256, 256, 0, stream>>>(xz, cwt, cbc, xc);
    // 5. dual-dir x-proj GEMM -> xd [2][BL,48] bf16 ([B|C|dtr] cols)
    gemm_mfma<5><<<dim3(2, 128), 256, 0, stream>>>(xc, 384, xpw, DM, xd, XDP, XDW, DM,
                                                   nullptr, nullptr, nullptr, nullptr, nullptr);
    // 6-8. chunked selective scan (dt fused) -> y [BL,384] bf16
    scan_partial<<<4 * NCH, 192, 0, stream>>>(xc, xd, dt_w0, dt_w1, dt_b0, dt_b1,
                                              A_log0, A_log1, Sb, Pb);
    scan_combine<<<48, 256, 0, stream>>>(Sb, Pb);
    scan_apply<<<4 * NCH, 192, 0, stream>>>(xc, xd, xz, dt_w0, dt_w1, dt_b0, dt_b1,
                                            A_log0, A_log1, D0, D1, Sb, yb);
    // 9. out-proj (packed K=384) * scale_mod -> xm [BL,192] bf16
    gemm_mfma<3><<<dim3(3, 128), 256, 0, stream>>>(yb, 384, wct, 384, xm, DM, DM, 384,
                                                   nullptr, scale_mod, nullptr, nullptr, nullptr);
    // 10. SGFN conv1x1 #1 -> t (reuses xz)
    gemm_mfma<1><<<dim3(12, 128), 256, 0, stream>>>(xm, DM, c1wb, DM, xz, 768, 768, DM,
                                                    c1b, nullptr, nullptr, nullptr, nullptr);
    // 11. depthwise 3x3 + gate -> g (reuses xc)
    dwgate_kernel<<<(BLR * 48) / 256, 256, 0, stream>>>(xz, dwt, dwb, xc);
    // 12. SGFN conv1x1 #2 + final residual -> d_out (fp32, NCHW)
    gemm_mfma<4><<<dim3(3, 128), 256, 0, stream>>>(xc, 384, c2wb, 384, nullptr, 0, DM, 384,
                                                   c2b, gamma, xm, x, (float*)d_out);
}